// Round 5
// baseline (231.025 us; speedup 1.0000x reference)
//
#include <hip/hip_runtime.h>

#define BB 2
#define LL 2048
#define DD 1024
#define HH 16
#define DHH 64

typedef _Float16 f16;
typedef _Float16 f16x8 __attribute__((ext_vector_type(8)));
typedef _Float16 f16x4 __attribute__((ext_vector_type(4)));
typedef _Float16 f16x2 __attribute__((ext_vector_type(2)));
typedef float f32x4 __attribute__((ext_vector_type(4)));
typedef unsigned long long u64;

#define VWAIT(N) asm volatile("s_waitcnt vmcnt(" #N ")" ::: "memory")
#define SB0() __builtin_amdgcn_sched_barrier(0)

__device__ __forceinline__ void gload_lds16(const void* g, void* l) {
    __builtin_amdgcn_global_load_lds(
        (const __attribute__((address_space(1))) void*)g,
        (__attribute__((address_space(3))) void*)l, 16, 0, 0);
}

// ---------------- f32 -> f16 conversion (vectorized) ----------------
__global__ void cvt_kernel(const float* __restrict__ src, f16* __restrict__ dst, int n4) {
    int i = blockIdx.x * blockDim.x + threadIdx.x;
    const int stride = gridDim.x * blockDim.x;
    for (; i < n4; i += stride) {
        float4 v = ((const float4*)src)[i];
        f16x4 o;
        o[0] = (f16)v.x; o[1] = (f16)v.y; o[2] = (f16)v.z; o[3] = (f16)v.w;
        ((f16x4*)dst)[i] = o;
    }
}

__global__ void cvt3_kernel(const float* __restrict__ a, const float* __restrict__ b,
                            const float* __restrict__ c,
                            f16* __restrict__ d0, f16* __restrict__ d1, f16* __restrict__ d2, int n4) {
    const float* s = blockIdx.y == 0 ? a : blockIdx.y == 1 ? b : c;
    f16* o = blockIdx.y == 0 ? d0 : blockIdx.y == 1 ? d1 : d2;
    int i = blockIdx.x * blockDim.x + threadIdx.x;
    const int stride = gridDim.x * blockDim.x;
    for (; i < n4; i += stride) {
        float4 v = ((const float4*)s)[i];
        f16x4 ov;
        ov[0] = (f16)v.x; ov[1] = (f16)v.y; ov[2] = (f16)v.z; ov[3] = (f16)v.w;
        ((f16x4*)o)[i] = ov;
    }
}

__global__ void cvt4_kernel(const float* __restrict__ a, const float* __restrict__ b,
                            const float* __restrict__ c, const float* __restrict__ d,
                            f16* __restrict__ dst, int n4) {
    const float* s = blockIdx.y == 0 ? a : blockIdx.y == 1 ? b : blockIdx.y == 2 ? c : d;
    f16* o = dst + (size_t)blockIdx.y * n4 * 4;
    int i = blockIdx.x * blockDim.x + threadIdx.x;
    const int stride = gridDim.x * blockDim.x;
    for (; i < n4; i += stride) {
        float4 v = ((const float4*)s)[i];
        f16x4 ov;
        ov[0] = (f16)v.x; ov[1] = (f16)v.y; ov[2] = (f16)v.z; ov[3] = (f16)v.w;
        ((f16x4*)o)[i] = ov;
    }
}

// ---------------- mask bit-packing, transposed layout: word[b][kt][q] ----------------
__global__ void pack_mask(const int* __restrict__ mask, u64* __restrict__ out, int nwords) {
    const int lane = threadIdx.x & 63;
    int w = (blockIdx.x * blockDim.x + threadIdx.x) >> 6;
    const int nw = (gridDim.x * blockDim.x) >> 6;
    for (; w < nwords; w += nw) {
        const int q = w & 2047;
        const int bk = w >> 11;          // b*32 + kt
        const int kt = bk & 31, b = bk >> 5;
        int mv = mask[((size_t)b * LL + q) * LL + kt * 64 + lane];
        u64 bits = __ballot(mv != 0);
        if (lane == 0) out[w] = bits;
    }
}

// ---------------- fused QKV projection GEMM (unchanged from round 4) ----------------
__global__ __launch_bounds__(256) void gemm_qkv(
        const f16* __restrict__ A0, const f16* __restrict__ A1, const f16* __restrict__ A2,
        const f16* __restrict__ W0, const f16* __restrict__ W1, const f16* __restrict__ W2,
        f16* __restrict__ C0, f16* __restrict__ C1, f16* __restrict__ C2,
        float scq, int zbase) {
    const int z = blockIdx.z + zbase;
    const f16* __restrict__ A = blockIdx.z == 0 ? A0 : blockIdx.z == 1 ? A1 : A2;
    const f16* __restrict__ W = blockIdx.z == 0 ? W0 : blockIdx.z == 1 ? W1 : W2;
    f16* __restrict__ C       = blockIdx.z == 0 ? C0 : blockIdx.z == 1 ? C1 : C2;
    const float scale = (z == 0) ? scq : 1.0f;

    __shared__ __align__(16) char lds[16384];
    const int tid = threadIdx.x, wid = tid >> 6, lane = tid & 63;
    const int m0 = blockIdx.y * 128, n0 = blockIdx.x * 128;
    const int lq = lane & 15, lg = lane >> 4;
    const int wm = (wid >> 1) << 6, wn = (wid & 1) << 6;
    f32x4 acc[4][4] = {};

    for (int kt = 0; kt < 32; ++kt) {
        #pragma unroll
        for (int j = 0; j < 2; ++j) {
            const int ldsoff = (wid * 2 + j) << 10;
            const int o = ldsoff + lane * 16;
            const int row = o >> 6;
            const int c8 = (o >> 4) & 3;
            gload_lds16(A + (size_t)(m0 + row) * DD + kt * 32 + c8 * 8, lds + ldsoff);
            gload_lds16(W + (size_t)(n0 + row) * DD + kt * 32 + c8 * 8, lds + 8192 + ldsoff);
        }
        __syncthreads();
        f16x8 af[4], bf[4];
        #pragma unroll
        for (int m = 0; m < 4; ++m)
            af[m] = *(const f16x8*)(lds + (wm + m * 16 + lq) * 64 + lg * 16);
        #pragma unroll
        for (int n = 0; n < 4; ++n)
            bf[n] = *(const f16x8*)(lds + 8192 + (wn + n * 16 + lq) * 64 + lg * 16);
        #pragma unroll
        for (int m = 0; m < 4; ++m)
            #pragma unroll
            for (int n = 0; n < 4; ++n)
                acc[m][n] = __builtin_amdgcn_mfma_f32_16x16x32_f16(af[m], bf[n], acc[m][n], 0, 0, 0);
        __syncthreads();
    }

    #pragma unroll
    for (int m = 0; m < 4; ++m)
        #pragma unroll
        for (int n = 0; n < 4; ++n)
            #pragma unroll
            for (int r = 0; r < 4; ++r) {
                const int row = m0 + wm + m * 16 + lg * 4 + r;
                const int col = n0 + wn + n * 16 + lq;
                const float v = acc[m][n][r] * scale;
                if (z < 2) {
                    C[(size_t)row * DD + col] = (f16)v;
                } else {
                    const int b = row >> 11, l = row & 2047;
                    const int h = col >> 6, dh = col & 63;
                    C[((size_t)((b * HH + h) * DHH + dh) << 11) + l] = (f16)v;
                }
            }
}

// ---------------- output projection GEMM (unchanged) ----------------
__global__ __launch_bounds__(256) void gemm_out(const f16* __restrict__ A, const f16* __restrict__ W,
                                                float* __restrict__ C) {
    __shared__ __align__(16) char lds[12288];
    const int tid = threadIdx.x, wid = tid >> 6, lane = tid & 63;
    const int m0 = blockIdx.y * 128, n0 = blockIdx.x * 64;
    const int lq = lane & 15, lg = lane >> 4;
    const int wm = wid * 32;
    f32x4 acc[2][4] = {};

    for (int kt = 0; kt < 32; ++kt) {
        #pragma unroll
        for (int j = 0; j < 2; ++j) {
            const int o = (j * 256 + tid) * 16;
            const int row = o >> 6, c8 = (o >> 4) & 3;
            gload_lds16(A + (size_t)(m0 + row) * DD + kt * 32 + c8 * 8,
                        lds + j * 4096 + (wid << 10));
        }
        {
            const int o = tid * 16;
            const int row = o >> 6, c8 = (o >> 4) & 3;
            gload_lds16(W + (size_t)(n0 + row) * DD + kt * 32 + c8 * 8,
                        lds + 8192 + (wid << 10));
        }
        __syncthreads();
        f16x8 af[2], bf[4];
        #pragma unroll
        for (int m = 0; m < 2; ++m)
            af[m] = *(const f16x8*)(lds + (wm + m * 16 + lq) * 64 + lg * 16);
        #pragma unroll
        for (int n = 0; n < 4; ++n)
            bf[n] = *(const f16x8*)(lds + 8192 + (n * 16 + lq) * 64 + lg * 16);
        #pragma unroll
        for (int m = 0; m < 2; ++m)
            #pragma unroll
            for (int n = 0; n < 4; ++n)
                acc[m][n] = __builtin_amdgcn_mfma_f32_16x16x32_f16(af[m], bf[n], acc[m][n], 0, 0, 0);
        __syncthreads();
    }

    #pragma unroll
    for (int m = 0; m < 2; ++m)
        #pragma unroll
        for (int n = 0; n < 4; ++n)
            #pragma unroll
            for (int r = 0; r < 4; ++r) {
                const int row = m0 + wm + m * 16 + lg * 4 + r;
                const int col = n0 + n * 16 + lq;
                C[(size_t)row * DD + col] = acc[m][n][r];
            }
}

// ---------------- Flash attention: QBLK=256, depth-2 counted-vmcnt pipeline ----------------
// Grid 256 blocks (1/CU), 8 waves x 32 q-rows. KVBLK=64, 3-buffer K/V/M rotation.
// Per iter, per wave: issue exactly 3 global_load_lds (K,V,M) for tile kt+2, then
// s_waitcnt vmcnt(3) (h!=0) / vmcnt(19|11) (h==0: +8 topP stores/iter in flight) +
// raw s_barrier. Loads span 2 full iterations; vmcnt never drains to 0 in the loop.
// LDS: P 32KB @0 (wave slice 4KB) | K 3x8KB @32768 | V 3x8KB @57344 | M 3x2KB @81920.
template<bool TOPF16>
__global__ __launch_bounds__(512) void attn_fwd(const f16* __restrict__ Qp, const f16* __restrict__ Kp,
                                                const f16* __restrict__ VTp,
                                                const u64* __restrict__ Mp,
                                                f16* __restrict__ Op, void* __restrict__ topout,
                                                float* __restrict__ statsLinv) {
    extern __shared__ char lds[];
    const int tid = threadIdx.x, wid = tid >> 6, lane = tid & 63;
    const int lq = lane & 15, lg = lane >> 4;
    // XCD-bijective swizzle: 8 consecutive qt-blocks of one (b,h) per XCD; 4 bh per XCD.
    const int d = blockIdx.x;
    const int qt = (d >> 3) & 7;
    const int bh = (d & 7) * 4 + (d >> 6);
    const int b = bh >> 4, h = bh & 15;
    const bool topblk = (h == 0);
    const int qrow0 = qt * 256 + wid * 32 + lq;
    const int qrow1 = qrow0 + 16;

    // ---- prologue: Q frags direct global->reg; stage K/V/M tiles 0 and 1 ----
    f16x8 qf0[2], qf1[2];
    #pragma unroll
    for (int kk = 0; kk < 2; ++kk) {
        qf0[kk] = *(const f16x8*)(Qp + (size_t)(b * LL + qrow0) * DD + h * 64 + (kk * 4 + lg) * 8);
        qf1[kk] = *(const f16x8*)(Qp + (size_t)(b * LL + qrow1) * DD + h * 64 + (kk * 4 + lg) * 8);
    }
    #pragma unroll
    for (int t = 0; t < 2; ++t) {
        const int o = tid * 16;
        const int row = o >> 7, sc = ((o >> 4) & 7) ^ (row & 7);
        gload_lds16(Kp + (size_t)(b * LL + t * 64 + row) * DD + h * 64 + sc * 8,
                    lds + 32768 + t * 8192 + (wid << 10));
        gload_lds16(VTp + (size_t)((b * HH + h) * DHH + row) * LL + t * 64 + sc * 8,
                    lds + 57344 + t * 8192 + (wid << 10));
        gload_lds16(Mp + (size_t)(b * 32 + t) * 2048 + qt * 256 + (wid & 1) * 128 + lane * 2,
                    lds + 81920 + t * 2048 + ((wid & 1) << 10));
    }

    float lsum0 = 0.f, lsum1 = 0.f;
    f32x4 acc0[4] = {}, acc1[4] = {};

    for (int kt = 0; kt < 32; ++kt) {
        // counted wait: K/V/M(kt) done; K/V/M(kt+1) [3] (+ topP stores x8 per older iter) stay in flight
        if (topblk) {
            if (kt == 0) { VWAIT(3); } else if (kt == 1) { VWAIT(11); } else { VWAIT(19); }
        } else {
            VWAIT(3);
        }
        SB0();
        __builtin_amdgcn_s_barrier();
        SB0();

        // issue tile kt+2 (clamped; junk re-stage of tile 31 at the tail keeps counts uniform)
        {
            const int nk = (kt + 2 < 32) ? kt + 2 : 31;
            const int nb = (kt + 2) % 3;
            const int o = tid * 16;
            const int row = o >> 7, sc = ((o >> 4) & 7) ^ (row & 7);
            gload_lds16(Kp + (size_t)(b * LL + nk * 64 + row) * DD + h * 64 + sc * 8,
                        lds + 32768 + nb * 8192 + (wid << 10));
            gload_lds16(VTp + (size_t)((b * HH + h) * DHH + row) * LL + nk * 64 + sc * 8,
                        lds + 57344 + nb * 8192 + (wid << 10));
            gload_lds16(Mp + (size_t)(b * 32 + nk) * 2048 + qt * 256 + (wid & 1) * 128 + lane * 2,
                        lds + 81920 + nb * 2048 + ((wid & 1) << 10));
        }
        SB0();

        const int cb = kt % 3;
        const char* Kb = lds + 32768 + cb * 8192;
        const char* Vb = lds + 57344 + cb * 8192;

        // masks for this tile from LDS
        const u64 cm0 = *(const u64*)(lds + 81920 + cb * 2048 + (wid * 32 + lq) * 8);
        const u64 cm1 = *(const u64*)(lds + 81920 + cb * 2048 + (wid * 32 + 16 + lq) * 8);

        // QK^T (swapped): s = mfma(K, Q) -> S^T[k][q]
        f32x4 s0[4] = {}, s1[4] = {};
        __builtin_amdgcn_s_setprio(1);
        #pragma unroll
        for (int f = 0; f < 4; ++f)
            #pragma unroll
            for (int kk = 0; kk < 2; ++kk) {
                const int co = (((kk * 4 + lg) ^ (lq & 7)) << 4);
                f16x8 kf = *(const f16x8*)(Kb + (f * 16 + lq) * 128 + co);
                s0[f] = __builtin_amdgcn_mfma_f32_16x16x32_f16(kf, qf0[kk], s0[f], 0, 0, 0);
                s1[f] = __builtin_amdgcn_mfma_f32_16x16x32_f16(kf, qf1[kk], s1[f], 0, 0, 0);
            }
        __builtin_amdgcn_s_setprio(0);

        // mask + exp2 + accumulate + pack (fixed-reference softmax, no max tracking)
        const u64 w0 = cm0 >> (lg * 4), w1 = cm1 >> (lg * 4);
        const unsigned lo0 = (unsigned)w0, hi0 = (unsigned)(w0 >> 32);
        const unsigned lo1 = (unsigned)w1, hi1 = (unsigned)(w1 >> 32);
        f16x4 ph0[4], ph1[4];
        #pragma unroll
        for (int f = 0; f < 4; ++f) {
            const unsigned nib0 = ((f < 2) ? (lo0 >> (f * 16)) : (hi0 >> ((f - 2) * 16))) & 0xFu;
            const unsigned nib1 = ((f < 2) ? (lo1 >> (f * 16)) : (hi1 >> ((f - 2) * 16))) & 0xFu;
            #pragma unroll
            for (int r = 0; r < 4; ++r) {
                if (nib0 & (1u << r)) s0[f][r] = -1e18f;
                if (nib1 & (1u << r)) s1[f][r] = -1e18f;
            }
            const float a0 = __builtin_amdgcn_exp2f(s0[f][0]);
            const float a1 = __builtin_amdgcn_exp2f(s0[f][1]);
            const float a2 = __builtin_amdgcn_exp2f(s0[f][2]);
            const float a3 = __builtin_amdgcn_exp2f(s0[f][3]);
            const float c0 = __builtin_amdgcn_exp2f(s1[f][0]);
            const float c1 = __builtin_amdgcn_exp2f(s1[f][1]);
            const float c2 = __builtin_amdgcn_exp2f(s1[f][2]);
            const float c3 = __builtin_amdgcn_exp2f(s1[f][3]);
            lsum0 += (a0 + a1) + (a2 + a3);
            lsum1 += (c0 + c1) + (c2 + c3);
            f16x2 pa = __builtin_bit_cast(f16x2, __builtin_amdgcn_cvt_pkrtz(a0, a1));
            f16x2 pb = __builtin_bit_cast(f16x2, __builtin_amdgcn_cvt_pkrtz(a2, a3));
            f16x2 pc = __builtin_bit_cast(f16x2, __builtin_amdgcn_cvt_pkrtz(c0, c1));
            f16x2 pd = __builtin_bit_cast(f16x2, __builtin_amdgcn_cvt_pkrtz(c2, c3));
            ph0[f][0] = pa[0]; ph0[f][1] = pa[1]; ph0[f][2] = pb[0]; ph0[f][3] = pb[1];
            ph1[f][0] = pc[0]; ph1[f][1] = pc[1]; ph1[f][2] = pd[0]; ph1[f][3] = pd[1];
        }

        if (topblk) {
            if (TOPF16) {
                f16* T = (f16*)topout;
                #pragma unroll
                for (int f = 0; f < 4; ++f) {
                    *(f16x4*)(T + ((size_t)b * LL + qrow0) * LL + kt * 64 + f * 16 + lg * 4) = ph0[f];
                    *(f16x4*)(T + ((size_t)b * LL + qrow1) * LL + kt * 64 + f * 16 + lg * 4) = ph1[f];
                }
            } else {
                float* T = (float*)topout;
                #pragma unroll
                for (int f = 0; f < 4; ++f) {
                    *(f32x4*)(T + ((size_t)b * LL + qrow0) * LL + kt * 64 + f * 16 + lg * 4) = s0[f];
                    *(f32x4*)(T + ((size_t)b * LL + qrow1) * LL + kt * 64 + f * 16 + lg * 4) = s1[f];
                }
            }
        }

        // P -> own wave's 4KB LDS slice (swizzled), rows lq (g0) and 16+lq (g1)
        #pragma unroll
        for (int f = 0; f < 4; ++f) {
            const int chunk = f * 2 + (lg >> 1);
            const int bo = ((chunk ^ (lq & 7)) << 4) + (lg & 1) * 8;
            *(f16x4*)(lds + (wid << 12) + lq * 128 + bo) = ph0[f];
            *(f16x4*)(lds + (wid << 12) + (16 + lq) * 128 + bo) = ph1[f];
        }

        // PV: acc += mfma(V^T_frag, P^T_frag)
        __builtin_amdgcn_s_setprio(1);
        #pragma unroll
        for (int kk = 0; kk < 2; ++kk) {
            const int co = (((kk * 4 + lg) ^ (lq & 7)) << 4);
            f16x8 pf0 = *(const f16x8*)(lds + (wid << 12) + lq * 128 + co);
            f16x8 pf1 = *(const f16x8*)(lds + (wid << 12) + (16 + lq) * 128 + co);
            #pragma unroll
            for (int f = 0; f < 4; ++f) {
                f16x8 vf = *(const f16x8*)(Vb + (f * 16 + lq) * 128 + co);
                acc0[f] = __builtin_amdgcn_mfma_f32_16x16x32_f16(vf, pf0, acc0[f], 0, 0, 0);
                acc1[f] = __builtin_amdgcn_mfma_f32_16x16x32_f16(vf, pf1, acc1[f], 0, 0, 0);
            }
        }
        __builtin_amdgcn_s_setprio(0);
    }

    lsum0 += __shfl_xor(lsum0, 16); lsum0 += __shfl_xor(lsum0, 32);
    lsum1 += __shfl_xor(lsum1, 16); lsum1 += __shfl_xor(lsum1, 32);
    const float linv0 = 1.f / lsum0, linv1 = 1.f / lsum1;
    #pragma unroll
    for (int f = 0; f < 4; ++f) {
        f16x4 ov0, ov1;
        #pragma unroll
        for (int r = 0; r < 4; ++r) {
            ov0[r] = (f16)(acc0[f][r] * linv0);
            ov1[r] = (f16)(acc1[f][r] * linv1);
        }
        *(f16x4*)(Op + (size_t)(b * LL + qrow0) * DD + h * 64 + f * 16 + lg * 4) = ov0;
        *(f16x4*)(Op + (size_t)(b * LL + qrow1) * DD + h * 64 + f * 16 + lg * 4) = ov1;
    }
    if (topblk && lg == 0) {
        statsLinv[(size_t)b * LL + qrow0] = linv0;
        statsLinv[(size_t)b * LL + qrow1] = linv1;
    }
}

// ---------------- top_attn finalize ----------------
template<bool TOPF16>
__global__ void norm_top(float* __restrict__ top, const void* __restrict__ src,
                         const float* __restrict__ linvp, int n) {
    int i = blockIdx.x * blockDim.x + threadIdx.x;
    const int stride = gridDim.x * blockDim.x;
    if (TOPF16) {
        const f16x8* s8 = (const f16x8*)src;
        for (; i < n; i += stride) {
            f16x8 v = s8[i];
            const float linv = linvp[(i * 8) >> 11];
            float4 a, bq;
            a.x = (float)v[0] * linv; a.y = (float)v[1] * linv;
            a.z = (float)v[2] * linv; a.w = (float)v[3] * linv;
            bq.x = (float)v[4] * linv; bq.y = (float)v[5] * linv;
            bq.z = (float)v[6] * linv; bq.w = (float)v[7] * linv;
            ((float4*)top)[i * 2] = a;
            ((float4*)top)[i * 2 + 1] = bq;
        }
    } else {
        for (; i < n; i += stride) {
            float4 v = ((const float4*)top)[i];
            const float linv = linvp[(i * 4) >> 11];
            v.x = __builtin_amdgcn_exp2f(v.x) * linv;
            v.y = __builtin_amdgcn_exp2f(v.y) * linv;
            v.z = __builtin_amdgcn_exp2f(v.z) * linv;
            v.w = __builtin_amdgcn_exp2f(v.w) * linv;
            ((float4*)top)[i] = v;
        }
    }
}

// ---------------- launch ----------------
extern "C" void kernel_launch(void* const* d_in, const int* in_sizes, int n_in,
                              void* d_out, int out_size, void* d_ws, size_t ws_size,
                              hipStream_t stream) {
    const float* q   = (const float*)d_in[0];
    const float* k   = (const float*)d_in[1];
    const float* v   = (const float*)d_in[2];
    const int*   msk = (const int*)d_in[3];
    const float* wq  = (const float*)d_in[4];
    const float* wk  = (const float*)d_in[5];
    const float* wv  = (const float*)d_in[6];
    const float* wo  = (const float*)d_in[7];
    float* out = (float*)d_out;

    const size_t NX = (size_t)BB * LL * DD;
    const size_t NW = (size_t)DD * DD;
    const int NMW = BB * LL * (LL / 64);
    const size_t NXo = NX;
    const float SCQ = 0.125f * 1.4426950408889634f;
    const int ALDS = 88064;  // 32K P + 24K K + 24K V + 6K M

    hipFuncSetAttribute(reinterpret_cast<const void*>(attn_fwd<true>),
                        hipFuncAttributeMaxDynamicSharedMemorySize, ALDS);
    hipFuncSetAttribute(reinterpret_cast<const void*>(attn_fwd<false>),
                        hipFuncAttributeMaxDynamicSharedMemorySize, ALDS);

    f16* ws = (f16*)d_ws;
    const size_t needed = (6 * NX + 4 * NW) * 2 + (size_t)NMW * 8 + (size_t)BB * LL * 4;
    const bool fused = ws_size >= needed;

    if (fused) {
        f16* bufQ = ws;
        f16* bufK = bufQ + NX;
        f16* bufV = bufK + NX;
        f16* topP = bufK;               // overlays bufK+bufV (dead by attn time)
        f16* wh   = bufV + NX;
        f16* wqh = wh, *wkh = wh + NW, *wvh = wh + 2 * NW, *woh = wh + 3 * NW;
        f16* Qp  = wh + 4 * NW;
        f16* Kp  = Qp + NX;
        f16* VTp = Kp + NX;
        u64* Mp  = (u64*)(VTp + NX);
        float* statsLinv = (float*)(Mp + NMW);

        pack_mask<<<256, 256, 0, stream>>>(msk, Mp, NMW);
        cvt4_kernel<<<dim3(128, 4), 256, 0, stream>>>(wq, wk, wv, wo, wh, (int)(NW / 4));
        cvt3_kernel<<<dim3(1024, 3), 256, 0, stream>>>(q, k, v, bufQ, bufK, bufV, (int)(NX / 4));
        gemm_qkv<<<dim3(8, 32, 3), 256, 0, stream>>>(bufQ, bufK, bufV, wqh, wkh, wvh,
                                                     Qp, Kp, VTp, SCQ, 0);
        attn_fwd<true><<<256, 512, ALDS, stream>>>(Qp, Kp, VTp, Mp, bufQ, topP, statsLinv);
        norm_top<true><<<2048, 256, 0, stream>>>(out + NXo, topP, statsLinv,
                                                 (int)((size_t)BB * LL * LL / 8));
        gemm_out<<<dim3(16, 32), 256, 0, stream>>>(bufQ, woh, out);
    } else {
        f16* bufA = ws;
        f16* wh   = bufA + NX;
        f16* wqh = wh, *wkh = wh + NW, *wvh = wh + 2 * NW, *woh = wh + 3 * NW;
        f16* Qp  = wh + 4 * NW;
        f16* Kp  = Qp + NX;
        f16* VTp = Kp + NX;
        u64* Mp  = (u64*)(VTp + NX);
        float* statsLinv = (float*)(Mp + NMW);

        pack_mask<<<256, 256, 0, stream>>>(msk, Mp, NMW);
        cvt4_kernel<<<dim3(128, 4), 256, 0, stream>>>(wq, wk, wv, wo, wh, (int)(NW / 4));
        cvt_kernel<<<2048, 256, 0, stream>>>(q, bufA, (int)(NX / 4));
        gemm_qkv<<<dim3(8, 32, 1), 256, 0, stream>>>(bufA, bufA, bufA, wqh, wqh, wqh,
                                                     Qp, Qp, Qp, SCQ, 0);
        cvt_kernel<<<2048, 256, 0, stream>>>(k, bufA, (int)(NX / 4));
        gemm_qkv<<<dim3(8, 32, 1), 256, 0, stream>>>(bufA, bufA, bufA, wkh, wkh, wkh,
                                                     Kp, Kp, Kp, SCQ, 1);
        cvt_kernel<<<2048, 256, 0, stream>>>(v, bufA, (int)(NX / 4));
        gemm_qkv<<<dim3(8, 32, 1), 256, 0, stream>>>(bufA, bufA, bufA, wvh, wvh, wvh,
                                                     VTp, VTp, VTp, SCQ, 2);
        attn_fwd<false><<<256, 512, ALDS, stream>>>(Qp, Kp, VTp, Mp, bufA,
                                                    out + NXo, statsLinv);
        norm_top<false><<<2048, 256, 0, stream>>>(out + NXo, out + NXo, statsLinv,
                                                  (int)((size_t)BB * LL * LL / 4));
        gemm_out<<<dim3(16, 32), 256, 0, stream>>>(bufA, woh, out);
    }
}

// Round 6
// 197.503 us; speedup vs baseline: 1.1697x; 1.1697x over previous
//
#include <hip/hip_runtime.h>

#define BB 2
#define LL 2048
#define DD 1024
#define HH 16
#define DHH 64

typedef _Float16 f16;
typedef _Float16 f16x8 __attribute__((ext_vector_type(8)));
typedef _Float16 f16x4 __attribute__((ext_vector_type(4)));
typedef _Float16 f16x2 __attribute__((ext_vector_type(2)));
typedef float f32x4 __attribute__((ext_vector_type(4)));
typedef unsigned long long u64;

#define VWAIT(N) asm volatile("s_waitcnt vmcnt(" #N ")" ::: "memory")
#define SB0() __builtin_amdgcn_sched_barrier(0)

__device__ __forceinline__ void gload_lds16(const void* g, void* l) {
    __builtin_amdgcn_global_load_lds(
        (const __attribute__((address_space(1))) void*)g,
        (__attribute__((address_space(3))) void*)l, 16, 0, 0);
}
__device__ __forceinline__ void gload_lds4(const void* g, void* l) {
    __builtin_amdgcn_global_load_lds(
        (const __attribute__((address_space(1))) void*)g,
        (__attribute__((address_space(3))) void*)l, 4, 0, 0);
}

// ---------------- f32 -> f16 conversion (vectorized) ----------------
__global__ void cvt_kernel(const float* __restrict__ src, f16* __restrict__ dst, int n4) {
    int i = blockIdx.x * blockDim.x + threadIdx.x;
    const int stride = gridDim.x * blockDim.x;
    for (; i < n4; i += stride) {
        float4 v = ((const float4*)src)[i];
        f16x4 o;
        o[0] = (f16)v.x; o[1] = (f16)v.y; o[2] = (f16)v.z; o[3] = (f16)v.w;
        ((f16x4*)dst)[i] = o;
    }
}

__global__ void cvt3_kernel(const float* __restrict__ a, const float* __restrict__ b,
                            const float* __restrict__ c,
                            f16* __restrict__ d0, f16* __restrict__ d1, f16* __restrict__ d2, int n4) {
    const float* s = blockIdx.y == 0 ? a : blockIdx.y == 1 ? b : c;
    f16* o = blockIdx.y == 0 ? d0 : blockIdx.y == 1 ? d1 : d2;
    int i = blockIdx.x * blockDim.x + threadIdx.x;
    const int stride = gridDim.x * blockDim.x;
    for (; i < n4; i += stride) {
        float4 v = ((const float4*)s)[i];
        f16x4 ov;
        ov[0] = (f16)v.x; ov[1] = (f16)v.y; ov[2] = (f16)v.z; ov[3] = (f16)v.w;
        ((f16x4*)o)[i] = ov;
    }
}

__global__ void cvt4_kernel(const float* __restrict__ a, const float* __restrict__ b,
                            const float* __restrict__ c, const float* __restrict__ d,
                            f16* __restrict__ dst, int n4) {
    const float* s = blockIdx.y == 0 ? a : blockIdx.y == 1 ? b : blockIdx.y == 2 ? c : d;
    f16* o = dst + (size_t)blockIdx.y * n4 * 4;
    int i = blockIdx.x * blockDim.x + threadIdx.x;
    const int stride = gridDim.x * blockDim.x;
    for (; i < n4; i += stride) {
        float4 v = ((const float4*)s)[i];
        f16x4 ov;
        ov[0] = (f16)v.x; ov[1] = (f16)v.y; ov[2] = (f16)v.z; ov[3] = (f16)v.w;
        ((f16x4*)o)[i] = ov;
    }
}

// ---------------- mask bit-packing: coalesced reads, transposed writes ----------------
// read-linear index w = (b*L + q)*32 + kt ; write out[(b*32 + kt)*L + q]
__global__ void pack_mask(const int* __restrict__ mask, u64* __restrict__ out, int nwords) {
    const int lane = threadIdx.x & 63;
    int w = (blockIdx.x * blockDim.x + threadIdx.x) >> 6;
    const int nw = (gridDim.x * blockDim.x) >> 6;
    for (; w < nwords; w += nw) {
        int mv = mask[(size_t)w * 64 + lane];
        u64 bits = __ballot(mv != 0);
        if (lane == 0) {
            const int kt = w & 31;
            const int bq = w >> 5;              // b*L + q
            const int q = bq & 2047, b = bq >> 11;
            out[((size_t)b * 32 + kt) * LL + q] = bits;
        }
    }
}

// ---------------- fused QKV projection GEMM (unchanged) ----------------
__global__ __launch_bounds__(256) void gemm_qkv(
        const f16* __restrict__ A0, const f16* __restrict__ A1, const f16* __restrict__ A2,
        const f16* __restrict__ W0, const f16* __restrict__ W1, const f16* __restrict__ W2,
        f16* __restrict__ C0, f16* __restrict__ C1, f16* __restrict__ C2,
        float scq, int zbase) {
    const int z = blockIdx.z + zbase;
    const f16* __restrict__ A = blockIdx.z == 0 ? A0 : blockIdx.z == 1 ? A1 : A2;
    const f16* __restrict__ W = blockIdx.z == 0 ? W0 : blockIdx.z == 1 ? W1 : W2;
    f16* __restrict__ C       = blockIdx.z == 0 ? C0 : blockIdx.z == 1 ? C1 : C2;
    const float scale = (z == 0) ? scq : 1.0f;

    __shared__ __align__(16) char lds[16384];
    const int tid = threadIdx.x, wid = tid >> 6, lane = tid & 63;
    const int m0 = blockIdx.y * 128, n0 = blockIdx.x * 128;
    const int lq = lane & 15, lg = lane >> 4;
    const int wm = (wid >> 1) << 6, wn = (wid & 1) << 6;
    f32x4 acc[4][4] = {};

    for (int kt = 0; kt < 32; ++kt) {
        #pragma unroll
        for (int j = 0; j < 2; ++j) {
            const int ldsoff = (wid * 2 + j) << 10;
            const int o = ldsoff + lane * 16;
            const int row = o >> 6;
            const int c8 = (o >> 4) & 3;
            gload_lds16(A + (size_t)(m0 + row) * DD + kt * 32 + c8 * 8, lds + ldsoff);
            gload_lds16(W + (size_t)(n0 + row) * DD + kt * 32 + c8 * 8, lds + 8192 + ldsoff);
        }
        __syncthreads();
        f16x8 af[4], bf[4];
        #pragma unroll
        for (int m = 0; m < 4; ++m)
            af[m] = *(const f16x8*)(lds + (wm + m * 16 + lq) * 64 + lg * 16);
        #pragma unroll
        for (int n = 0; n < 4; ++n)
            bf[n] = *(const f16x8*)(lds + 8192 + (wn + n * 16 + lq) * 64 + lg * 16);
        #pragma unroll
        for (int m = 0; m < 4; ++m)
            #pragma unroll
            for (int n = 0; n < 4; ++n)
                acc[m][n] = __builtin_amdgcn_mfma_f32_16x16x32_f16(af[m], bf[n], acc[m][n], 0, 0, 0);
        __syncthreads();
    }

    #pragma unroll
    for (int m = 0; m < 4; ++m)
        #pragma unroll
        for (int n = 0; n < 4; ++n)
            #pragma unroll
            for (int r = 0; r < 4; ++r) {
                const int row = m0 + wm + m * 16 + lg * 4 + r;
                const int col = n0 + wn + n * 16 + lq;
                const float v = acc[m][n][r] * scale;
                if (z < 2) {
                    C[(size_t)row * DD + col] = (f16)v;
                } else {
                    const int b = row >> 11, l = row & 2047;
                    const int h = col >> 6, dh = col & 63;
                    C[((size_t)((b * HH + h) * DHH + dh) << 11) + l] = (f16)v;
                }
            }
}

// ---------------- output projection GEMM (unchanged) ----------------
__global__ __launch_bounds__(256) void gemm_out(const f16* __restrict__ A, const f16* __restrict__ W,
                                                float* __restrict__ C) {
    __shared__ __align__(16) char lds[12288];
    const int tid = threadIdx.x, wid = tid >> 6, lane = tid & 63;
    const int m0 = blockIdx.y * 128, n0 = blockIdx.x * 64;
    const int lq = lane & 15, lg = lane >> 4;
    const int wm = wid * 32;
    f32x4 acc[2][4] = {};

    for (int kt = 0; kt < 32; ++kt) {
        #pragma unroll
        for (int j = 0; j < 2; ++j) {
            const int o = (j * 256 + tid) * 16;
            const int row = o >> 6, c8 = (o >> 4) & 3;
            gload_lds16(A + (size_t)(m0 + row) * DD + kt * 32 + c8 * 8,
                        lds + j * 4096 + (wid << 10));
        }
        {
            const int o = tid * 16;
            const int row = o >> 6, c8 = (o >> 4) & 3;
            gload_lds16(W + (size_t)(n0 + row) * DD + kt * 32 + c8 * 8,
                        lds + 8192 + (wid << 10));
        }
        __syncthreads();
        f16x8 af[2], bf[4];
        #pragma unroll
        for (int m = 0; m < 2; ++m)
            af[m] = *(const f16x8*)(lds + (wm + m * 16 + lq) * 64 + lg * 16);
        #pragma unroll
        for (int n = 0; n < 4; ++n)
            bf[n] = *(const f16x8*)(lds + 8192 + (n * 16 + lq) * 64 + lg * 16);
        #pragma unroll
        for (int m = 0; m < 2; ++m)
            #pragma unroll
            for (int n = 0; n < 4; ++n)
                acc[m][n] = __builtin_amdgcn_mfma_f32_16x16x32_f16(af[m], bf[n], acc[m][n], 0, 0, 0);
        __syncthreads();
    }

    #pragma unroll
    for (int m = 0; m < 2; ++m)
        #pragma unroll
        for (int n = 0; n < 4; ++n)
            #pragma unroll
            for (int r = 0; r < 4; ++r) {
                const int row = m0 + wm + m * 16 + lg * 4 + r;
                const int col = n0 + n * 16 + lq;
                C[(size_t)row * DD + col] = acc[m][n][r];
            }
}

// ---------------- Flash attention: 4 waves, QBLK=128, 2 blocks/CU, counted vmcnt ----------------
// Grid 512 (2 blocks/CU co-resident -> two independent barrier-phase groups per CU).
// 4 waves x 32 q-rows. KVBLK=64, 3-buffer K/V/M rotation, depth-2 prefetch.
// Per iter per wave: 5 global_load_lds (2 K, 2 V, 1 M) for tile kt+2, then
// s_waitcnt vmcnt(5) (topblk: 21/13/5) + raw s_barrier. vmcnt never 0 in the loop.
// LDS 67KB: P 16K @0 (4K/wave) | K 3x8K @16384 | V 3x8K @40960 | M 3x1K @65536.
template<bool TOPF16>
__global__ __launch_bounds__(256) void attn_fwd(const f16* __restrict__ Qp, const f16* __restrict__ Kp,
                                                const f16* __restrict__ VTp,
                                                const u64* __restrict__ Mp,
                                                f16* __restrict__ Op, void* __restrict__ topout,
                                                float* __restrict__ statsLinv) {
    extern __shared__ char lds[];
    const int tid = threadIdx.x, wid = tid >> 6, lane = tid & 63;
    const int lq = lane & 15, lg = lane >> 4;
    // XCD swizzle (HW: block i -> XCD i%8): 4 (b,h) x 16 qt per XCD -> 2MB K/V set in L2
    const int d = blockIdx.x;
    const int xcd = d & 7, j = d >> 3;          // j 0..63
    const int bh = xcd * 4 + (j >> 4);          // 0..31
    const int qt = j & 15;
    const int b = bh >> 4, h = bh & 15;
    const bool topblk = (h == 0);
    const int qrow0 = qt * 128 + wid * 32 + lq;
    const int qrow1 = qrow0 + 16;

    // ---- prologue: Q frags global->reg, then stage K/V/M tiles 0 and 1 ----
    f16x8 qf0[2], qf1[2];
    #pragma unroll
    for (int kk = 0; kk < 2; ++kk) {
        qf0[kk] = *(const f16x8*)(Qp + (size_t)(b * LL + qrow0) * DD + h * 64 + (kk * 4 + lg) * 8);
        qf1[kk] = *(const f16x8*)(Qp + (size_t)(b * LL + qrow1) * DD + h * 64 + (kk * 4 + lg) * 8);
    }
    #pragma unroll
    for (int t = 0; t < 2; ++t) {
        #pragma unroll
        for (int jj = 0; jj < 2; ++jj) {
            const int o = (wid * 2 + jj) * 1024 + lane * 16;
            const int row = o >> 7, sc = ((o >> 4) & 7) ^ (row & 7);
            gload_lds16(Kp + (size_t)(b * LL + t * 64 + row) * DD + h * 64 + sc * 8,
                        lds + 16384 + t * 8192 + (wid * 2 + jj) * 1024);
            gload_lds16(VTp + (size_t)((b * HH + h) * DHH + row) * LL + t * 64 + sc * 8,
                        lds + 40960 + t * 8192 + (wid * 2 + jj) * 1024);
        }
        gload_lds4((const char*)Mp + (((size_t)b * 32 + t) * LL + qt * 128 + wid * 32) * 8 + lane * 4,
                   lds + 65536 + t * 1024 + wid * 256);
    }

    float lsum0 = 0.f, lsum1 = 0.f;
    f32x4 acc0[4] = {}, acc1[4] = {};

    for (int kt = 0; kt < 32; ++kt) {
        // counted wait: tile kt's 5 loads done; kt+1's 5 (+ older topP stores) in flight
        if (topblk) {
            if (kt == 0) { VWAIT(5); } else if (kt == 1) { VWAIT(13); } else { VWAIT(21); }
        } else {
            VWAIT(5);
        }
        SB0();
        __builtin_amdgcn_s_barrier();
        SB0();

        // issue tile kt+2 (clamped junk re-stage at tail keeps counts uniform)
        {
            const int nk = (kt + 2 < 32) ? kt + 2 : 31;
            const int nb = (kt + 2) % 3;
            #pragma unroll
            for (int jj = 0; jj < 2; ++jj) {
                const int o = (wid * 2 + jj) * 1024 + lane * 16;
                const int row = o >> 7, sc = ((o >> 4) & 7) ^ (row & 7);
                gload_lds16(Kp + (size_t)(b * LL + nk * 64 + row) * DD + h * 64 + sc * 8,
                            lds + 16384 + nb * 8192 + (wid * 2 + jj) * 1024);
                gload_lds16(VTp + (size_t)((b * HH + h) * DHH + row) * LL + nk * 64 + sc * 8,
                            lds + 40960 + nb * 8192 + (wid * 2 + jj) * 1024);
            }
            gload_lds4((const char*)Mp + (((size_t)b * 32 + nk) * LL + qt * 128 + wid * 32) * 8 + lane * 4,
                       lds + 65536 + nb * 1024 + wid * 256);
        }
        SB0();

        const int cb = kt % 3;
        const char* Kb = lds + 16384 + cb * 8192;
        const char* Vb = lds + 40960 + cb * 8192;
        const u64 cm0 = *(const u64*)(lds + 65536 + cb * 1024 + (wid * 32 + lq) * 8);
        const u64 cm1 = *(const u64*)(lds + 65536 + cb * 1024 + (wid * 32 + 16 + lq) * 8);

        // QK^T (swapped): s = mfma(K, Q) -> S^T[k][q]
        f32x4 s0[4] = {}, s1[4] = {};
        __builtin_amdgcn_s_setprio(1);
        #pragma unroll
        for (int f = 0; f < 4; ++f)
            #pragma unroll
            for (int kk = 0; kk < 2; ++kk) {
                const int co = (((kk * 4 + lg) ^ (lq & 7)) << 4);
                f16x8 kf = *(const f16x8*)(Kb + (f * 16 + lq) * 128 + co);
                s0[f] = __builtin_amdgcn_mfma_f32_16x16x32_f16(kf, qf0[kk], s0[f], 0, 0, 0);
                s1[f] = __builtin_amdgcn_mfma_f32_16x16x32_f16(kf, qf1[kk], s1[f], 0, 0, 0);
            }
        __builtin_amdgcn_s_setprio(0);

        // mask + exp2 + accumulate + pack (fixed-reference softmax)
        const u64 w0 = cm0 >> (lg * 4), w1 = cm1 >> (lg * 4);
        const unsigned lo0 = (unsigned)w0, hi0 = (unsigned)(w0 >> 32);
        const unsigned lo1 = (unsigned)w1, hi1 = (unsigned)(w1 >> 32);
        f16x4 ph0[4], ph1[4];
        #pragma unroll
        for (int f = 0; f < 4; ++f) {
            const unsigned nib0 = ((f < 2) ? (lo0 >> (f * 16)) : (hi0 >> ((f - 2) * 16))) & 0xFu;
            const unsigned nib1 = ((f < 2) ? (lo1 >> (f * 16)) : (hi1 >> ((f - 2) * 16))) & 0xFu;
            #pragma unroll
            for (int r = 0; r < 4; ++r) {
                if (nib0 & (1u << r)) s0[f][r] = -1e18f;
                if (nib1 & (1u << r)) s1[f][r] = -1e18f;
            }
            const float a0 = __builtin_amdgcn_exp2f(s0[f][0]);
            const float a1 = __builtin_amdgcn_exp2f(s0[f][1]);
            const float a2 = __builtin_amdgcn_exp2f(s0[f][2]);
            const float a3 = __builtin_amdgcn_exp2f(s0[f][3]);
            const float c0 = __builtin_amdgcn_exp2f(s1[f][0]);
            const float c1 = __builtin_amdgcn_exp2f(s1[f][1]);
            const float c2 = __builtin_amdgcn_exp2f(s1[f][2]);
            const float c3 = __builtin_amdgcn_exp2f(s1[f][3]);
            lsum0 += (a0 + a1) + (a2 + a3);
            lsum1 += (c0 + c1) + (c2 + c3);
            f16x2 pa = __builtin_bit_cast(f16x2, __builtin_amdgcn_cvt_pkrtz(a0, a1));
            f16x2 pb = __builtin_bit_cast(f16x2, __builtin_amdgcn_cvt_pkrtz(a2, a3));
            f16x2 pc = __builtin_bit_cast(f16x2, __builtin_amdgcn_cvt_pkrtz(c0, c1));
            f16x2 pd = __builtin_bit_cast(f16x2, __builtin_amdgcn_cvt_pkrtz(c2, c3));
            ph0[f][0] = pa[0]; ph0[f][1] = pa[1]; ph0[f][2] = pb[0]; ph0[f][3] = pb[1];
            ph1[f][0] = pc[0]; ph1[f][1] = pc[1]; ph1[f][2] = pd[0]; ph1[f][3] = pd[1];
        }

        if (topblk) {
            if (TOPF16) {
                f16* T = (f16*)topout;
                #pragma unroll
                for (int f = 0; f < 4; ++f) {
                    *(f16x4*)(T + ((size_t)b * LL + qrow0) * LL + kt * 64 + f * 16 + lg * 4) = ph0[f];
                    *(f16x4*)(T + ((size_t)b * LL + qrow1) * LL + kt * 64 + f * 16 + lg * 4) = ph1[f];
                }
            } else {
                float* T = (float*)topout;
                #pragma unroll
                for (int f = 0; f < 4; ++f) {
                    *(f32x4*)(T + ((size_t)b * LL + qrow0) * LL + kt * 64 + f * 16 + lg * 4) = s0[f];
                    *(f32x4*)(T + ((size_t)b * LL + qrow1) * LL + kt * 64 + f * 16 + lg * 4) = s1[f];
                }
            }
        }

        // P -> own wave's 4KB LDS slice (swizzled)
        #pragma unroll
        for (int f = 0; f < 4; ++f) {
            const int chunk = f * 2 + (lg >> 1);
            const int bo = ((chunk ^ (lq & 7)) << 4) + (lg & 1) * 8;
            *(f16x4*)(lds + (wid << 12) + lq * 128 + bo) = ph0[f];
            *(f16x4*)(lds + (wid << 12) + (16 + lq) * 128 + bo) = ph1[f];
        }

        // PV: acc += mfma(V^T_frag, P^T_frag)
        __builtin_amdgcn_s_setprio(1);
        #pragma unroll
        for (int kk = 0; kk < 2; ++kk) {
            const int co = (((kk * 4 + lg) ^ (lq & 7)) << 4);
            f16x8 pf0 = *(const f16x8*)(lds + (wid << 12) + lq * 128 + co);
            f16x8 pf1 = *(const f16x8*)(lds + (wid << 12) + (16 + lq) * 128 + co);
            #pragma unroll
            for (int f = 0; f < 4; ++f) {
                f16x8 vf = *(const f16x8*)(Vb + (f * 16 + lq) * 128 + co);
                acc0[f] = __builtin_amdgcn_mfma_f32_16x16x32_f16(vf, pf0, acc0[f], 0, 0, 0);
                acc1[f] = __builtin_amdgcn_mfma_f32_16x16x32_f16(vf, pf1, acc1[f], 0, 0, 0);
            }
        }
        __builtin_amdgcn_s_setprio(0);
    }

    lsum0 += __shfl_xor(lsum0, 16); lsum0 += __shfl_xor(lsum0, 32);
    lsum1 += __shfl_xor(lsum1, 16); lsum1 += __shfl_xor(lsum1, 32);
    const float linv0 = 1.f / lsum0, linv1 = 1.f / lsum1;
    #pragma unroll
    for (int f = 0; f < 4; ++f) {
        f16x4 ov0, ov1;
        #pragma unroll
        for (int r = 0; r < 4; ++r) {
            ov0[r] = (f16)(acc0[f][r] * linv0);
            ov1[r] = (f16)(acc1[f][r] * linv1);
        }
        *(f16x4*)(Op + (size_t)(b * LL + qrow0) * DD + h * 64 + f * 16 + lg * 4) = ov0;
        *(f16x4*)(Op + (size_t)(b * LL + qrow1) * DD + h * 64 + f * 16 + lg * 4) = ov1;
    }
    if (topblk && lg == 0) {
        statsLinv[(size_t)b * LL + qrow0] = linv0;
        statsLinv[(size_t)b * LL + qrow1] = linv1;
    }
}

// ---------------- top_attn finalize ----------------
template<bool TOPF16>
__global__ void norm_top(float* __restrict__ top, const void* __restrict__ src,
                         const float* __restrict__ linvp, int n) {
    int i = blockIdx.x * blockDim.x + threadIdx.x;
    const int stride = gridDim.x * blockDim.x;
    if (TOPF16) {
        const f16x8* s8 = (const f16x8*)src;
        for (; i < n; i += stride) {
            f16x8 v = s8[i];
            const float linv = linvp[(i * 8) >> 11];
            float4 a, bq;
            a.x = (float)v[0] * linv; a.y = (float)v[1] * linv;
            a.z = (float)v[2] * linv; a.w = (float)v[3] * linv;
            bq.x = (float)v[4] * linv; bq.y = (float)v[5] * linv;
            bq.z = (float)v[6] * linv; bq.w = (float)v[7] * linv;
            ((float4*)top)[i * 2] = a;
            ((float4*)top)[i * 2 + 1] = bq;
        }
    } else {
        for (; i < n; i += stride) {
            float4 v = ((const float4*)top)[i];
            const float linv = linvp[(i * 4) >> 11];
            v.x = __builtin_amdgcn_exp2f(v.x) * linv;
            v.y = __builtin_amdgcn_exp2f(v.y) * linv;
            v.z = __builtin_amdgcn_exp2f(v.z) * linv;
            v.w = __builtin_amdgcn_exp2f(v.w) * linv;
            ((float4*)top)[i] = v;
        }
    }
}

// ---------------- launch ----------------
extern "C" void kernel_launch(void* const* d_in, const int* in_sizes, int n_in,
                              void* d_out, int out_size, void* d_ws, size_t ws_size,
                              hipStream_t stream) {
    const float* q   = (const float*)d_in[0];
    const float* k   = (const float*)d_in[1];
    const float* v   = (const float*)d_in[2];
    const int*   msk = (const int*)d_in[3];
    const float* wq  = (const float*)d_in[4];
    const float* wk  = (const float*)d_in[5];
    const float* wv  = (const float*)d_in[6];
    const float* wo  = (const float*)d_in[7];
    float* out = (float*)d_out;

    const size_t NX = (size_t)BB * LL * DD;
    const size_t NW = (size_t)DD * DD;
    const int NMW = BB * LL * (LL / 64);
    const size_t NXo = NX;
    const float SCQ = 0.125f * 1.4426950408889634f;
    const int ALDS = 68608;  // 16K P + 24K K + 24K V + 3K M

    hipFuncSetAttribute(reinterpret_cast<const void*>(attn_fwd<true>),
                        hipFuncAttributeMaxDynamicSharedMemorySize, ALDS);
    hipFuncSetAttribute(reinterpret_cast<const void*>(attn_fwd<false>),
                        hipFuncAttributeMaxDynamicSharedMemorySize, ALDS);

    f16* ws = (f16*)d_ws;
    const size_t needed = (6 * NX + 4 * NW) * 2 + (size_t)NMW * 8 + (size_t)BB * LL * 4;
    const bool fused = ws_size >= needed;

    if (fused) {
        f16* bufQ = ws;
        f16* bufK = bufQ + NX;
        f16* bufV = bufK + NX;
        f16* topP = bufK;               // overlays bufK+bufV (dead by attn time)
        f16* wh   = bufV + NX;
        f16* wqh = wh, *wkh = wh + NW, *wvh = wh + 2 * NW, *woh = wh + 3 * NW;
        f16* Qp  = wh + 4 * NW;
        f16* Kp  = Qp + NX;
        f16* VTp = Kp + NX;
        u64* Mp  = (u64*)(VTp + NX);
        float* statsLinv = (float*)(Mp + NMW);

        pack_mask<<<256, 256, 0, stream>>>(msk, Mp, NMW);
        cvt4_kernel<<<dim3(128, 4), 256, 0, stream>>>(wq, wk, wv, wo, wh, (int)(NW / 4));
        cvt3_kernel<<<dim3(1024, 3), 256, 0, stream>>>(q, k, v, bufQ, bufK, bufV, (int)(NX / 4));
        gemm_qkv<<<dim3(8, 32, 3), 256, 0, stream>>>(bufQ, bufK, bufV, wqh, wkh, wvh,
                                                     Qp, Kp, VTp, SCQ, 0);
        attn_fwd<true><<<512, 256, ALDS, stream>>>(Qp, Kp, VTp, Mp, bufQ, topP, statsLinv);
        norm_top<true><<<2048, 256, 0, stream>>>(out + NXo, topP, statsLinv,
                                                 (int)((size_t)BB * LL * LL / 8));
        gemm_out<<<dim3(16, 32), 256, 0, stream>>>(bufQ, woh, out);
    } else {
        f16* bufA = ws;
        f16* wh   = bufA + NX;
        f16* wqh = wh, *wkh = wh + NW, *wvh = wh + 2 * NW, *woh = wh + 3 * NW;
        f16* Qp  = wh + 4 * NW;
        f16* Kp  = Qp + NX;
        f16* VTp = Kp + NX;
        u64* Mp  = (u64*)(VTp + NX);
        float* statsLinv = (float*)(Mp + NMW);

        pack_mask<<<256, 256, 0, stream>>>(msk, Mp, NMW);
        cvt4_kernel<<<dim3(128, 4), 256, 0, stream>>>(wq, wk, wv, wo, wh, (int)(NW / 4));
        cvt_kernel<<<2048, 256, 0, stream>>>(q, bufA, (int)(NX / 4));
        gemm_qkv<<<dim3(8, 32, 1), 256, 0, stream>>>(bufA, bufA, bufA, wqh, wqh, wqh,
                                                     Qp, Qp, Qp, SCQ, 0);
        cvt_kernel<<<2048, 256, 0, stream>>>(k, bufA, (int)(NX / 4));
        gemm_qkv<<<dim3(8, 32, 1), 256, 0, stream>>>(bufA, bufA, bufA, wkh, wkh, wkh,
                                                     Kp, Kp, Kp, SCQ, 1);
        cvt_kernel<<<2048, 256, 0, stream>>>(v, bufA, (int)(NX / 4));
        gemm_qkv<<<dim3(8, 32, 1), 256, 0, stream>>>(bufA, bufA, bufA, wvh, wvh, wvh,
                                                     VTp, VTp, VTp, SCQ, 2);
        attn_fwd<false><<<512, 256, ALDS, stream>>>(Qp, Kp, VTp, Mp, bufA,
                                                    out + NXo, statsLinv);
        norm_top<false><<<2048, 256, 0, stream>>>(out + NXo, out + NXo, statsLinv,
                                                  (int)((size_t)BB * LL * LL / 4));
        gemm_out<<<dim3(16, 32), 256, 0, stream>>>(bufA, woh, out);
    }
}

// Round 7
// 167.659 us; speedup vs baseline: 1.3779x; 1.1780x over previous
//
#include <hip/hip_runtime.h>

#define BB 2
#define LL 2048
#define DD 1024
#define HH 16
#define DHH 64

typedef _Float16 f16;
typedef _Float16 f16x8 __attribute__((ext_vector_type(8)));
typedef _Float16 f16x4 __attribute__((ext_vector_type(4)));
typedef _Float16 f16x2 __attribute__((ext_vector_type(2)));
typedef float f32x4 __attribute__((ext_vector_type(4)));
typedef unsigned long long u64;

#define VWAIT(N) asm volatile("s_waitcnt vmcnt(" #N ")" ::: "memory")
#define SB0() __builtin_amdgcn_sched_barrier(0)

__device__ __forceinline__ void gload_lds16(const void* g, void* l) {
    __builtin_amdgcn_global_load_lds(
        (const __attribute__((address_space(1))) void*)g,
        (__attribute__((address_space(3))) void*)l, 16, 0, 0);
}

__device__ __forceinline__ f16x4 cvt4f(float4 v) {
    f16x4 o;
    o[0] = (f16)v.x; o[1] = (f16)v.y; o[2] = (f16)v.z; o[3] = (f16)v.w;
    return o;
}

// ---------------- fused prep: mask pack + all f32->f16 conversions ----------------
// blockIdx.y: 0 = mask pack (transposed write), 1 = 4 weight matrices -> wh,
// 2/3/4 = q/k/v -> bufQ/K/V (q pre-scaled by scq).
__global__ void prep(const float* __restrict__ q, const float* __restrict__ k,
                     const float* __restrict__ v, const int* __restrict__ msk,
                     const float* __restrict__ wq, const float* __restrict__ wk,
                     const float* __restrict__ wv, const float* __restrict__ wo,
                     f16* __restrict__ bufQ, f16* __restrict__ bufK, f16* __restrict__ bufV,
                     f16* __restrict__ wh, u64* __restrict__ Mp, float scq) {
    const int tid = threadIdx.x;
    const int y = blockIdx.y;
    if (y == 0) {
        // pack: word w = (b*L+q)*32 + kt (coalesced reads); write Mp[(b*32+kt)*L + q]
        const int lane = tid & 63;
        int w = (blockIdx.x * 256 + tid) >> 6;
        const int nw = (1024 * 256) >> 6;
        for (; w < BB * LL * 32; w += nw) {
            int mv = msk[(size_t)w * 64 + lane];
            u64 bits = __ballot(mv != 0);
            if (lane == 0) {
                const int kt = w & 31;
                const int bq = w >> 5;
                const int qq = bq & 2047, b = bq >> 11;
                Mp[((size_t)b * 32 + kt) * LL + qq] = bits;
            }
        }
    } else if (y == 1) {
        // weights: i in f16x4 units over [wq|wk|wv|wo]; NW/4 = 2^18 per matrix
        int i = blockIdx.x * 256 + tid;
        const int stride = 1024 * 256;
        for (; i < 4 * 262144; i += stride) {
            const int sel = i >> 18, j = i & 262143;
            const float* s = sel == 0 ? wq : sel == 1 ? wk : sel == 2 ? wv : wo;
            ((f16x4*)wh)[i] = cvt4f(((const float4*)s)[j]);
        }
    } else {
        const float* s = y == 2 ? q : y == 3 ? k : v;
        f16* o = y == 2 ? bufQ : y == 3 ? bufK : bufV;
        const float sc = y == 2 ? scq : 1.0f;
        int i = blockIdx.x * 256 + tid;
        const int stride = 1024 * 256;
        for (; i < (int)(BB * LL * DD / 4); i += stride) {
            float4 vv = ((const float4*)s)[i];
            vv.x *= sc; vv.y *= sc; vv.z *= sc; vv.w *= sc;
            ((f16x4*)o)[i] = cvt4f(vv);
        }
    }
}

// standalone pieces for the fallback path
__global__ void cvt_kernel(const float* __restrict__ src, f16* __restrict__ dst, int n4, float sc) {
    int i = blockIdx.x * blockDim.x + threadIdx.x;
    const int stride = gridDim.x * blockDim.x;
    for (; i < n4; i += stride) {
        float4 v = ((const float4*)src)[i];
        v.x *= sc; v.y *= sc; v.z *= sc; v.w *= sc;
        ((f16x4*)dst)[i] = cvt4f(v);
    }
}
__global__ void cvt4_kernel(const float* __restrict__ a, const float* __restrict__ b,
                            const float* __restrict__ c, const float* __restrict__ d,
                            f16* __restrict__ dst, int n4) {
    const float* s = blockIdx.y == 0 ? a : blockIdx.y == 1 ? b : blockIdx.y == 2 ? c : d;
    f16* o = dst + (size_t)blockIdx.y * n4 * 4;
    int i = blockIdx.x * blockDim.x + threadIdx.x;
    const int stride = gridDim.x * blockDim.x;
    for (; i < n4; i += stride)
        ((f16x4*)o)[i] = cvt4f(((const float4*)s)[i]);
}
__global__ void pack_mask(const int* __restrict__ mask, u64* __restrict__ out, int nwords) {
    const int lane = threadIdx.x & 63;
    int w = (blockIdx.x * blockDim.x + threadIdx.x) >> 6;
    const int nw = (gridDim.x * blockDim.x) >> 6;
    for (; w < nwords; w += nw) {
        int mv = mask[(size_t)w * 64 + lane];
        u64 bits = __ballot(mv != 0);
        if (lane == 0) {
            const int kt = w & 31;
            const int bq = w >> 5;
            const int qq = bq & 2047, b = bq >> 11;
            out[((size_t)b * 32 + kt) * LL + qq] = bits;
        }
    }
}

// ---------------- GEMM core: C = A @ W^T, 128x128 tile, BK=32 ----------------
// z: 0 -> Q (f16 row-major), 1 -> K (f16 row-major), 2 -> V transposed-head [b][h][dh][L]
__device__ __forceinline__ void gemm_core(const f16* __restrict__ A, const f16* __restrict__ W,
                                          f16* __restrict__ C, int z, int xb, int yb, char* lds) {
    const int tid = threadIdx.x, wid = tid >> 6, lane = tid & 63;
    const int m0 = yb * 128, n0 = xb * 128;
    const int lq = lane & 15, lg = lane >> 4;
    const int wm = (wid >> 1) << 6, wn = (wid & 1) << 6;
    f32x4 acc[4][4] = {};

    for (int kt = 0; kt < 32; ++kt) {
        #pragma unroll
        for (int j = 0; j < 2; ++j) {
            const int ldsoff = (wid * 2 + j) << 10;
            const int o = ldsoff + lane * 16;
            const int row = o >> 6;
            const int c8 = (o >> 4) & 3;
            gload_lds16(A + (size_t)(m0 + row) * DD + kt * 32 + c8 * 8, lds + ldsoff);
            gload_lds16(W + (size_t)(n0 + row) * DD + kt * 32 + c8 * 8, lds + 8192 + ldsoff);
        }
        __syncthreads();
        f16x8 af[4], bf[4];
        #pragma unroll
        for (int m = 0; m < 4; ++m)
            af[m] = *(const f16x8*)(lds + (wm + m * 16 + lq) * 64 + lg * 16);
        #pragma unroll
        for (int n = 0; n < 4; ++n)
            bf[n] = *(const f16x8*)(lds + 8192 + (wn + n * 16 + lq) * 64 + lg * 16);
        #pragma unroll
        for (int m = 0; m < 4; ++m)
            #pragma unroll
            for (int n = 0; n < 4; ++n)
                acc[m][n] = __builtin_amdgcn_mfma_f32_16x16x32_f16(af[m], bf[n], acc[m][n], 0, 0, 0);
        __syncthreads();
    }

    #pragma unroll
    for (int m = 0; m < 4; ++m)
        #pragma unroll
        for (int n = 0; n < 4; ++n)
            #pragma unroll
            for (int r = 0; r < 4; ++r) {
                const int row = m0 + wm + m * 16 + lg * 4 + r;
                const int col = n0 + wn + n * 16 + lq;
                const float val = acc[m][n][r];
                if (z < 2) {
                    C[(size_t)row * DD + col] = (f16)val;
                } else {
                    const int b = row >> 11, l = row & 2047;
                    const int h = col >> 6, dh = col & 63;
                    C[((size_t)((b * HH + h) * DHH + dh) << 11) + l] = (f16)val;
                }
            }
}

// fused QKV: 768 blocks 1D, XCD-swizzled so the 8 N-tiles sharing one A-panel sit on one XCD
__global__ __launch_bounds__(256) void gemm_qkv(
        const f16* __restrict__ A0, const f16* __restrict__ A1, const f16* __restrict__ A2,
        const f16* __restrict__ W0, const f16* __restrict__ W1, const f16* __restrict__ W2,
        f16* __restrict__ C0, f16* __restrict__ C1, f16* __restrict__ C2) {
    __shared__ __align__(16) char lds[16384];
    const int bid = blockIdx.x;
    const int xcd = bid & 7, j = bid >> 3;      // j 0..95
    const int p = xcd * 12 + (j >> 3);          // A-panel index 0..95
    const int xb = j & 7;
    const int z = p >> 5, yb = p & 31;
    const f16* A = z == 0 ? A0 : z == 1 ? A1 : A2;
    const f16* W = z == 0 ? W0 : z == 1 ? W1 : W2;
    f16* C       = z == 0 ? C0 : z == 1 ? C1 : C2;
    gemm_core(A, W, C, z, xb, yb, lds);
}

// fallback single GEMM (no swizzle)
__global__ __launch_bounds__(256) void gemm_one(const f16* __restrict__ A, const f16* __restrict__ W,
                                                f16* __restrict__ C, int z) {
    __shared__ __align__(16) char lds[16384];
    gemm_core(A, W, C, z, blockIdx.x, blockIdx.y, lds);
}

// ---------------- output projection GEMM: 128x64 tile, 512 blocks 1D, XCD-swizzled ----------------
__global__ __launch_bounds__(256) void gemm_out(const f16* __restrict__ A, const f16* __restrict__ W,
                                                float* __restrict__ C) {
    __shared__ __align__(16) char lds[12288];
    const int bid = blockIdx.x;
    const int xcd = bid & 7, j = bid >> 3;      // j 0..63
    const int yb = xcd * 4 + (j >> 4);          // M-panel 0..31, 4 per XCD
    const int xb = j & 15;                      // N-tile 0..15
    const int tid = threadIdx.x, wid = tid >> 6, lane = tid & 63;
    const int m0 = yb * 128, n0 = xb * 64;
    const int lq = lane & 15, lg = lane >> 4;
    const int wm = wid * 32;
    f32x4 acc[2][4] = {};

    for (int kt = 0; kt < 32; ++kt) {
        #pragma unroll
        for (int j2 = 0; j2 < 2; ++j2) {
            const int o = (j2 * 256 + tid) * 16;
            const int row = o >> 6, c8 = (o >> 4) & 3;
            gload_lds16(A + (size_t)(m0 + row) * DD + kt * 32 + c8 * 8,
                        lds + j2 * 4096 + (wid << 10));
        }
        {
            const int o = tid * 16;
            const int row = o >> 6, c8 = (o >> 4) & 3;
            gload_lds16(W + (size_t)(n0 + row) * DD + kt * 32 + c8 * 8,
                        lds + 8192 + (wid << 10));
        }
        __syncthreads();
        f16x8 af[2], bf[4];
        #pragma unroll
        for (int m = 0; m < 2; ++m)
            af[m] = *(const f16x8*)(lds + (wm + m * 16 + lq) * 64 + lg * 16);
        #pragma unroll
        for (int n = 0; n < 4; ++n)
            bf[n] = *(const f16x8*)(lds + 8192 + (n * 16 + lq) * 64 + lg * 16);
        #pragma unroll
        for (int m = 0; m < 2; ++m)
            #pragma unroll
            for (int n = 0; n < 4; ++n)
                acc[m][n] = __builtin_amdgcn_mfma_f32_16x16x32_f16(af[m], bf[n], acc[m][n], 0, 0, 0);
        __syncthreads();
    }

    #pragma unroll
    for (int m = 0; m < 2; ++m)
        #pragma unroll
        for (int n = 0; n < 4; ++n)
            #pragma unroll
            for (int r = 0; r < 4; ++r) {
                const int row = m0 + wm + m * 16 + lg * 4 + r;
                const int col = n0 + n * 16 + lq;
                C[(size_t)row * DD + col] = acc[m][n][r];
            }
}

// ---------------- Flash attention: QBLK=64, 4 waves, 4 blocks/CU, depth-1 counted pipeline ----------------
// Grid 1024 (4 blocks/CU), 4 waves x 16 q-rows. KVBLK=64, 2-buffer K/V.
// Per iter: VWAIT(topblk&&kt>0 ? 4 : 0) -> s_barrier -> plain mask load -> issue 4 staged
// loads for tile kt+1 -> compute. Mask load pinned BEFORE staged issues so the compiler's
// auto-wait for it (vmcnt(4)) never drains the staged pipeline. topblk's 4 P-stores stay
// in flight across the wait. LDS 40KB: P 4x2K @0 | K 2x8K @8192 | V 2x8K @24576.
template<bool TOPF16>
__global__ __launch_bounds__(256) void attn_fwd(const f16* __restrict__ Qp, const f16* __restrict__ Kp,
                                                const f16* __restrict__ VTp,
                                                const u64* __restrict__ Mp,
                                                f16* __restrict__ Op, void* __restrict__ topout,
                                                float* __restrict__ statsLinv) {
    extern __shared__ char lds[];
    const int tid = threadIdx.x, wid = tid >> 6, lane = tid & 63;
    const int lq = lane & 15, lg = lane >> 4;
    // XCD swizzle: 4 (b,h) x 32 qt per XCD -> 2MB K/V working set per XCD L2
    const int bid = blockIdx.x;
    const int xcd = bid & 7, j = bid >> 3;      // j 0..127
    const int bh = xcd * 4 + (j >> 5);          // 0..31
    const int qt = j & 31;
    const int b = bh >> 4, h = bh & 15;
    const bool topblk = (h == 0);
    const int qrow = qt * 64 + wid * 16 + lq;

    // Q frags (plain global->reg)
    f16x8 qf[2];
    #pragma unroll
    for (int kk = 0; kk < 2; ++kk)
        qf[kk] = *(const f16x8*)(Qp + (size_t)(b * LL + qrow) * DD + h * 64 + (kk * 4 + lg) * 8);

    // prologue: stage tile 0 into buffer 0
    {
        #pragma unroll
        for (int jj = 0; jj < 2; ++jj) {
            const int o = (wid * 2 + jj) * 1024 + lane * 16;
            const int row = o >> 7, sc = ((o >> 4) & 7) ^ (row & 7);
            gload_lds16(Kp + (size_t)(b * LL + row) * DD + h * 64 + sc * 8,
                        lds + 8192 + (wid * 2 + jj) * 1024);
            gload_lds16(VTp + (size_t)((b * HH + h) * DHH + row) * LL + sc * 8,
                        lds + 24576 + (wid * 2 + jj) * 1024);
        }
    }

    float lsum = 0.f;
    f32x4 acc[4] = {};

    for (int kt = 0; kt < 32; ++kt) {
        if (topblk && kt > 0) { VWAIT(4); } else { VWAIT(0); }
        SB0();
        __builtin_amdgcn_s_barrier();
        SB0();
        // mask for this tile: plain load, pinned before staged issues
        const u64 cm = Mp[((size_t)b * 32 + kt) * LL + qrow];
        SB0();
        // issue tile kt+1 into the other buffer (junk re-stage of 31 at tail)
        {
            const int nk = (kt + 1 < 32) ? kt + 1 : 31;
            const int nb = (kt + 1) & 1;
            #pragma unroll
            for (int jj = 0; jj < 2; ++jj) {
                const int o = (wid * 2 + jj) * 1024 + lane * 16;
                const int row = o >> 7, sc = ((o >> 4) & 7) ^ (row & 7);
                gload_lds16(Kp + (size_t)(b * LL + nk * 64 + row) * DD + h * 64 + sc * 8,
                            lds + 8192 + nb * 8192 + (wid * 2 + jj) * 1024);
                gload_lds16(VTp + (size_t)((b * HH + h) * DHH + row) * LL + nk * 64 + sc * 8,
                            lds + 24576 + nb * 8192 + (wid * 2 + jj) * 1024);
            }
        }
        SB0();

        const int cb = kt & 1;
        const char* Kb = lds + 8192 + cb * 8192;
        const char* Vb = lds + 24576 + cb * 8192;

        // QK^T (swapped): s = mfma(K, Q) -> S^T[k][q]
        f32x4 s[4] = {};
        __builtin_amdgcn_s_setprio(1);
        #pragma unroll
        for (int f = 0; f < 4; ++f)
            #pragma unroll
            for (int kk = 0; kk < 2; ++kk) {
                const int co = (((kk * 4 + lg) ^ (lq & 7)) << 4);
                f16x8 kf = *(const f16x8*)(Kb + (f * 16 + lq) * 128 + co);
                s[f] = __builtin_amdgcn_mfma_f32_16x16x32_f16(kf, qf[kk], s[f], 0, 0, 0);
            }
        __builtin_amdgcn_s_setprio(0);

        // mask + exp2 + accumulate + pack (fixed-reference softmax)
        const u64 wsh = cm >> (lg * 4);
        const unsigned lo = (unsigned)wsh, hi = (unsigned)(wsh >> 32);
        f16x4 ph[4];
        #pragma unroll
        for (int f = 0; f < 4; ++f) {
            const unsigned nib = ((f < 2) ? (lo >> (f * 16)) : (hi >> ((f - 2) * 16))) & 0xFu;
            #pragma unroll
            for (int r = 0; r < 4; ++r)
                if (nib & (1u << r)) s[f][r] = -1e18f;
            const float p0 = __builtin_amdgcn_exp2f(s[f][0]);
            const float p1 = __builtin_amdgcn_exp2f(s[f][1]);
            const float p2 = __builtin_amdgcn_exp2f(s[f][2]);
            const float p3 = __builtin_amdgcn_exp2f(s[f][3]);
            lsum += (p0 + p1) + (p2 + p3);
            f16x2 pa = __builtin_bit_cast(f16x2, __builtin_amdgcn_cvt_pkrtz(p0, p1));
            f16x2 pb = __builtin_bit_cast(f16x2, __builtin_amdgcn_cvt_pkrtz(p2, p3));
            ph[f][0] = pa[0]; ph[f][1] = pa[1]; ph[f][2] = pb[0]; ph[f][3] = pb[1];
        }

        if (topblk) {
            if (TOPF16) {
                f16* T = (f16*)topout;
                #pragma unroll
                for (int f = 0; f < 4; ++f)
                    *(f16x4*)(T + ((size_t)b * LL + qrow) * LL + kt * 64 + f * 16 + lg * 4) = ph[f];
            } else {
                float* T = (float*)topout;
                #pragma unroll
                for (int f = 0; f < 4; ++f)
                    *(f32x4*)(T + ((size_t)b * LL + qrow) * LL + kt * 64 + f * 16 + lg * 4) = s[f];
            }
        }

        // P -> own wave's 2KB LDS slice (swizzled)
        #pragma unroll
        for (int f = 0; f < 4; ++f) {
            const int chunk = f * 2 + (lg >> 1);
            const int bo = ((chunk ^ (lq & 7)) << 4) + (lg & 1) * 8;
            *(f16x4*)(lds + (wid << 11) + lq * 128 + bo) = ph[f];
        }

        // PV: acc += mfma(V^T_frag, P^T_frag)
        __builtin_amdgcn_s_setprio(1);
        #pragma unroll
        for (int kk = 0; kk < 2; ++kk) {
            const int co = (((kk * 4 + lg) ^ (lq & 7)) << 4);
            f16x8 pf = *(const f16x8*)(lds + (wid << 11) + lq * 128 + co);
            #pragma unroll
            for (int f = 0; f < 4; ++f) {
                f16x8 vf = *(const f16x8*)(Vb + (f * 16 + lq) * 128 + co);
                acc[f] = __builtin_amdgcn_mfma_f32_16x16x32_f16(vf, pf, acc[f], 0, 0, 0);
            }
        }
        __builtin_amdgcn_s_setprio(0);
    }

    lsum += __shfl_xor(lsum, 16);
    lsum += __shfl_xor(lsum, 32);
    const float linv = 1.f / lsum;
    #pragma unroll
    for (int f = 0; f < 4; ++f) {
        f16x4 ov;
        #pragma unroll
        for (int r = 0; r < 4; ++r) ov[r] = (f16)(acc[f][r] * linv);
        *(f16x4*)(Op + (size_t)(b * LL + qrow) * DD + h * 64 + f * 16 + lg * 4) = ov;
    }
    if (topblk && lg == 0) statsLinv[(size_t)b * LL + qrow] = linv;
}

// ---------------- top_attn finalize ----------------
template<bool TOPF16>
__global__ void norm_top(float* __restrict__ top, const void* __restrict__ src,
                         const float* __restrict__ linvp, int n) {
    int i = blockIdx.x * blockDim.x + threadIdx.x;
    const int stride = gridDim.x * blockDim.x;
    if (TOPF16) {
        const f16x8* s8 = (const f16x8*)src;
        for (; i < n; i += stride) {
            f16x8 v = s8[i];
            const float linv = linvp[(i * 8) >> 11];
            float4 a, bq;
            a.x = (float)v[0] * linv; a.y = (float)v[1] * linv;
            a.z = (float)v[2] * linv; a.w = (float)v[3] * linv;
            bq.x = (float)v[4] * linv; bq.y = (float)v[5] * linv;
            bq.z = (float)v[6] * linv; bq.w = (float)v[7] * linv;
            ((float4*)top)[i * 2] = a;
            ((float4*)top)[i * 2 + 1] = bq;
        }
    } else {
        for (; i < n; i += stride) {
            float4 v = ((const float4*)top)[i];
            const float linv = linvp[(i * 4) >> 11];
            v.x = __builtin_amdgcn_exp2f(v.x) * linv;
            v.y = __builtin_amdgcn_exp2f(v.y) * linv;
            v.z = __builtin_amdgcn_exp2f(v.z) * linv;
            v.w = __builtin_amdgcn_exp2f(v.w) * linv;
            ((float4*)top)[i] = v;
        }
    }
}

// ---------------- launch ----------------
extern "C" void kernel_launch(void* const* d_in, const int* in_sizes, int n_in,
                              void* d_out, int out_size, void* d_ws, size_t ws_size,
                              hipStream_t stream) {
    const float* q   = (const float*)d_in[0];
    const float* k   = (const float*)d_in[1];
    const float* v   = (const float*)d_in[2];
    const int*   msk = (const int*)d_in[3];
    const float* wq  = (const float*)d_in[4];
    const float* wk  = (const float*)d_in[5];
    const float* wv  = (const float*)d_in[6];
    const float* wo  = (const float*)d_in[7];
    float* out = (float*)d_out;

    const size_t NX = (size_t)BB * LL * DD;
    const size_t NW = (size_t)DD * DD;
    const int NMW = BB * LL * (LL / 64);
    const size_t NXo = NX;
    const float SCQ = 0.125f * 1.4426950408889634f;
    const int ALDS = 40960;  // P 8K + K 16K + V 16K

    f16* ws = (f16*)d_ws;
    const size_t needed = (6 * NX + 4 * NW) * 2 + (size_t)NMW * 8 + (size_t)BB * LL * 4;
    const bool fused = ws_size >= needed;

    if (fused) {
        f16* bufQ = ws;
        f16* bufK = bufQ + NX;
        f16* bufV = bufK + NX;
        f16* topP = bufK;               // overlays bufK+bufV (dead by attn time)
        f16* wh   = bufV + NX;
        f16* wqh = wh, *wkh = wh + NW, *wvh = wh + 2 * NW, *woh = wh + 3 * NW;
        f16* Qp  = wh + 4 * NW;
        f16* Kp  = Qp + NX;
        f16* VTp = Kp + NX;
        u64* Mp  = (u64*)(VTp + NX);
        float* statsLinv = (float*)(Mp + NMW);

        prep<<<dim3(1024, 5), 256, 0, stream>>>(q, k, v, msk, wq, wk, wv, wo,
                                                bufQ, bufK, bufV, wh, Mp, SCQ);
        gemm_qkv<<<768, 256, 0, stream>>>(bufQ, bufK, bufV, wqh, wkh, wvh, Qp, Kp, VTp);
        attn_fwd<true><<<1024, 256, ALDS, stream>>>(Qp, Kp, VTp, Mp, bufQ, topP, statsLinv);
        norm_top<true><<<2048, 256, 0, stream>>>(out + NXo, topP, statsLinv,
                                                 (int)((size_t)BB * LL * LL / 8));
        gemm_out<<<512, 256, 0, stream>>>(bufQ, woh, out);
    } else {
        f16* bufA = ws;
        f16* wh   = bufA + NX;
        f16* wqh = wh, *wkh = wh + NW, *wvh = wh + 2 * NW, *woh = wh + 3 * NW;
        f16* Qp  = wh + 4 * NW;
        f16* Kp  = Qp + NX;
        f16* VTp = Kp + NX;
        u64* Mp  = (u64*)(VTp + NX);
        float* statsLinv = (float*)(Mp + NMW);

        pack_mask<<<256, 256, 0, stream>>>(msk, Mp, NMW);
        cvt4_kernel<<<dim3(128, 4), 256, 0, stream>>>(wq, wk, wv, wo, wh, (int)(NW / 4));
        cvt_kernel<<<2048, 256, 0, stream>>>(q, bufA, (int)(NX / 4), SCQ);
        gemm_one<<<dim3(8, 32), 256, 0, stream>>>(bufA, wqh, Qp, 0);
        cvt_kernel<<<2048, 256, 0, stream>>>(k, bufA, (int)(NX / 4), 1.f);
        gemm_one<<<dim3(8, 32), 256, 0, stream>>>(bufA, wkh, Kp, 1);
        cvt_kernel<<<2048, 256, 0, stream>>>(v, bufA, (int)(NX / 4), 1.f);
        gemm_one<<<dim3(8, 32), 256, 0, stream>>>(bufA, wvh, VTp, 2);
        attn_fwd<false><<<1024, 256, ALDS, stream>>>(Qp, Kp, VTp, Mp, bufA,
                                                     out + NXo, statsLinv);
        norm_top<false><<<2048, 256, 0, stream>>>(out + NXo, out + NXo, statsLinv,
                                                  (int)((size_t)BB * LL * LL / 4));
        gemm_out<<<512, 256, 0, stream>>>(bufA, woh, out);
    }
}

// Round 8
// 167.039 us; speedup vs baseline: 1.3831x; 1.0037x over previous
//
#include <hip/hip_runtime.h>

#define BB 2
#define LL 2048
#define DD 1024
#define HH 16
#define DHH 64

typedef _Float16 f16;
typedef _Float16 f16x8 __attribute__((ext_vector_type(8)));
typedef _Float16 f16x4 __attribute__((ext_vector_type(4)));
typedef _Float16 f16x2 __attribute__((ext_vector_type(2)));
typedef float f32x4 __attribute__((ext_vector_type(4)));
typedef unsigned long long u64;

#define VWAIT(N) asm volatile("s_waitcnt vmcnt(" #N ")" ::: "memory")
#define SB0() __builtin_amdgcn_sched_barrier(0)

__device__ __forceinline__ void gload_lds16(const void* g, void* l) {
    __builtin_amdgcn_global_load_lds(
        (const __attribute__((address_space(1))) void*)g,
        (__attribute__((address_space(3))) void*)l, 16, 0, 0);
}

__device__ __forceinline__ f16x4 cvt4f(float4 v) {
    f16x4 o;
    o[0] = (f16)v.x; o[1] = (f16)v.y; o[2] = (f16)v.z; o[3] = (f16)v.w;
    return o;
}

// ---------------- fused prep: mask pack + all f32->f16 conversions ----------------
__global__ void prep(const float* __restrict__ q, const float* __restrict__ k,
                     const float* __restrict__ v, const int* __restrict__ msk,
                     const float* __restrict__ wq, const float* __restrict__ wk,
                     const float* __restrict__ wv, const float* __restrict__ wo,
                     f16* __restrict__ bufQ, f16* __restrict__ bufK, f16* __restrict__ bufV,
                     f16* __restrict__ wh, u64* __restrict__ Mp, float scq) {
    const int tid = threadIdx.x;
    const int y = blockIdx.y;
    if (y == 0) {
        const int lane = tid & 63;
        int w = (blockIdx.x * 256 + tid) >> 6;
        const int nw = (1024 * 256) >> 6;
        for (; w < BB * LL * 32; w += nw) {
            int mv = msk[(size_t)w * 64 + lane];
            u64 bits = __ballot(mv != 0);
            if (lane == 0) {
                const int kt = w & 31;
                const int bq = w >> 5;
                const int qq = bq & 2047, b = bq >> 11;
                Mp[((size_t)b * 32 + kt) * LL + qq] = bits;
            }
        }
    } else if (y == 1) {
        int i = blockIdx.x * 256 + tid;
        const int stride = 1024 * 256;
        for (; i < 4 * 262144; i += stride) {
            const int sel = i >> 18, j = i & 262143;
            const float* s = sel == 0 ? wq : sel == 1 ? wk : sel == 2 ? wv : wo;
            ((f16x4*)wh)[i] = cvt4f(((const float4*)s)[j]);
        }
    } else {
        const float* s = y == 2 ? q : y == 3 ? k : v;
        f16* o = y == 2 ? bufQ : y == 3 ? bufK : bufV;
        const float sc = y == 2 ? scq : 1.0f;
        int i = blockIdx.x * 256 + tid;
        const int stride = 1024 * 256;
        for (; i < (int)(BB * LL * DD / 4); i += stride) {
            float4 vv = ((const float4*)s)[i];
            vv.x *= sc; vv.y *= sc; vv.z *= sc; vv.w *= sc;
            ((f16x4*)o)[i] = cvt4f(vv);
        }
    }
}

// standalone pieces for the fallback path
__global__ void cvt_kernel(const float* __restrict__ src, f16* __restrict__ dst, int n4, float sc) {
    int i = blockIdx.x * blockDim.x + threadIdx.x;
    const int stride = gridDim.x * blockDim.x;
    for (; i < n4; i += stride) {
        float4 v = ((const float4*)src)[i];
        v.x *= sc; v.y *= sc; v.z *= sc; v.w *= sc;
        ((f16x4*)dst)[i] = cvt4f(v);
    }
}
__global__ void cvt4_kernel(const float* __restrict__ a, const float* __restrict__ b,
                            const float* __restrict__ c, const float* __restrict__ d,
                            f16* __restrict__ dst, int n4) {
    const float* s = blockIdx.y == 0 ? a : blockIdx.y == 1 ? b : blockIdx.y == 2 ? c : d;
    f16* o = dst + (size_t)blockIdx.y * n4 * 4;
    int i = blockIdx.x * blockDim.x + threadIdx.x;
    const int stride = gridDim.x * blockDim.x;
    for (; i < n4; i += stride)
        ((f16x4*)o)[i] = cvt4f(((const float4*)s)[i]);
}
__global__ void pack_mask(const int* __restrict__ mask, u64* __restrict__ out, int nwords) {
    const int lane = threadIdx.x & 63;
    int w = (blockIdx.x * blockDim.x + threadIdx.x) >> 6;
    const int nw = (gridDim.x * blockDim.x) >> 6;
    for (; w < nwords; w += nw) {
        int mv = mask[(size_t)w * 64 + lane];
        u64 bits = __ballot(mv != 0);
        if (lane == 0) {
            const int kt = w & 31;
            const int bq = w >> 5;
            const int qq = bq & 2047, b = bq >> 11;
            out[((size_t)b * 32 + kt) * LL + qq] = bits;
        }
    }
}

// ---------------- GEMM core: C = A @ W^T, 128x128 tile, BK=32 ----------------
// 3-buffer LDS, depth-2 prefetch, counted VWAIT(4), single raw barrier per iter.
// LDS 48KB: A 3x8K @0 | B 3x8K @24576.
// z: 0/1 -> f16 row-major out; 2 -> V transposed-head [b][h][dh][L]
__device__ __forceinline__ void gemm_core(const f16* __restrict__ A, const f16* __restrict__ W,
                                          f16* __restrict__ C, int z, int xb, int yb, char* lds) {
    const int tid = threadIdx.x, wid = tid >> 6, lane = tid & 63;
    const int m0 = yb * 128, n0 = xb * 128;
    const int lq = lane & 15, lg = lane >> 4;
    const int wm = (wid >> 1) << 6, wn = (wid & 1) << 6;
    f32x4 acc[4][4] = {};

    // prologue: stage tiles 0 and 1
    #pragma unroll
    for (int t = 0; t < 2; ++t)
        #pragma unroll
        for (int j = 0; j < 2; ++j) {
            const int ldsoff = (wid * 2 + j) << 10;
            const int o = ldsoff + lane * 16;
            const int row = o >> 6, c8 = (o >> 4) & 3;
            gload_lds16(A + (size_t)(m0 + row) * DD + t * 32 + c8 * 8, lds + t * 8192 + ldsoff);
            gload_lds16(W + (size_t)(n0 + row) * DD + t * 32 + c8 * 8, lds + 24576 + t * 8192 + ldsoff);
        }

    for (int kt = 0; kt < 32; ++kt) {
        VWAIT(4);            // tile kt done; tile kt+1 (4 loads/wave) stays in flight
        SB0();
        __builtin_amdgcn_s_barrier();
        SB0();
        {
            const int nk = (kt + 2 < 32) ? kt + 2 : 31;   // junk re-stage at tail keeps counts uniform
            const int nb = (kt + 2) % 3;
            #pragma unroll
            for (int j = 0; j < 2; ++j) {
                const int ldsoff = (wid * 2 + j) << 10;
                const int o = ldsoff + lane * 16;
                const int row = o >> 6, c8 = (o >> 4) & 3;
                gload_lds16(A + (size_t)(m0 + row) * DD + nk * 32 + c8 * 8,
                            lds + nb * 8192 + ldsoff);
                gload_lds16(W + (size_t)(n0 + row) * DD + nk * 32 + c8 * 8,
                            lds + 24576 + nb * 8192 + ldsoff);
            }
        }
        SB0();

        const int cb = kt % 3;
        const char* Ab = lds + cb * 8192;
        const char* Bb = lds + 24576 + cb * 8192;
        f16x8 af[4], bf[4];
        #pragma unroll
        for (int m = 0; m < 4; ++m)
            af[m] = *(const f16x8*)(Ab + (wm + m * 16 + lq) * 64 + lg * 16);
        #pragma unroll
        for (int n = 0; n < 4; ++n)
            bf[n] = *(const f16x8*)(Bb + (wn + n * 16 + lq) * 64 + lg * 16);
        __builtin_amdgcn_s_setprio(1);
        #pragma unroll
        for (int m = 0; m < 4; ++m)
            #pragma unroll
            for (int n = 0; n < 4; ++n)
                acc[m][n] = __builtin_amdgcn_mfma_f32_16x16x32_f16(af[m], bf[n], acc[m][n], 0, 0, 0);
        __builtin_amdgcn_s_setprio(0);
    }

    #pragma unroll
    for (int m = 0; m < 4; ++m)
        #pragma unroll
        for (int n = 0; n < 4; ++n)
            #pragma unroll
            for (int r = 0; r < 4; ++r) {
                const int row = m0 + wm + m * 16 + lg * 4 + r;
                const int col = n0 + wn + n * 16 + lq;
                const float val = acc[m][n][r];
                if (z < 2) {
                    C[(size_t)row * DD + col] = (f16)val;
                } else {
                    const int b = row >> 11, l = row & 2047;
                    const int h = col >> 6, dh = col & 63;
                    C[((size_t)((b * HH + h) * DHH + dh) << 11) + l] = (f16)val;
                }
            }
}

// fused QKV: 768 blocks 1D, XCD-swizzled so the 8 N-tiles sharing one A-panel sit on one XCD
__global__ __launch_bounds__(256) void gemm_qkv(
        const f16* __restrict__ A0, const f16* __restrict__ A1, const f16* __restrict__ A2,
        const f16* __restrict__ W0, const f16* __restrict__ W1, const f16* __restrict__ W2,
        f16* __restrict__ C0, f16* __restrict__ C1, f16* __restrict__ C2) {
    __shared__ __align__(16) char lds[49152];
    const int bid = blockIdx.x;
    const int xcd = bid & 7, j = bid >> 3;      // j 0..95
    const int p = xcd * 12 + (j >> 3);          // A-panel index 0..95
    const int xb = j & 7;
    const int z = p >> 5, yb = p & 31;
    const f16* A = z == 0 ? A0 : z == 1 ? A1 : A2;
    const f16* W = z == 0 ? W0 : z == 1 ? W1 : W2;
    f16* C       = z == 0 ? C0 : z == 1 ? C1 : C2;
    gemm_core(A, W, C, z, xb, yb, lds);
}

// fallback single GEMM (no swizzle)
__global__ __launch_bounds__(256) void gemm_one(const f16* __restrict__ A, const f16* __restrict__ W,
                                                f16* __restrict__ C, int z) {
    __shared__ __align__(16) char lds[49152];
    gemm_core(A, W, C, z, blockIdx.x, blockIdx.y, lds);
}

// ---------------- output projection GEMM: 128x64 tile, 512 blocks 1D, XCD-swizzled ----------------
// 3-buffer depth-2 counted pipeline: 3 loads/wave/iter -> VWAIT(3).
// LDS 36KB: A 3x8K @0 | W 3x4K @24576.
__global__ __launch_bounds__(256) void gemm_out(const f16* __restrict__ A, const f16* __restrict__ W,
                                                float* __restrict__ C) {
    __shared__ __align__(16) char lds[36864];
    const int bid = blockIdx.x;
    const int xcd = bid & 7, j = bid >> 3;      // j 0..63
    const int yb = xcd * 4 + (j >> 4);          // M-panel 0..31, 4 per XCD
    const int xb = j & 15;                      // N-tile 0..15
    const int tid = threadIdx.x, wid = tid >> 6, lane = tid & 63;
    const int m0 = yb * 128, n0 = xb * 64;
    const int lq = lane & 15, lg = lane >> 4;
    const int wm = wid * 32;
    f32x4 acc[2][4] = {};

    #pragma unroll
    for (int t = 0; t < 2; ++t) {
        #pragma unroll
        for (int j2 = 0; j2 < 2; ++j2) {
            const int o = (j2 * 256 + tid) * 16;
            const int row = o >> 6, c8 = (o >> 4) & 3;
            gload_lds16(A + (size_t)(m0 + row) * DD + t * 32 + c8 * 8,
                        lds + t * 8192 + j2 * 4096 + (wid << 10));
        }
        {
            const int o = tid * 16;
            const int row = o >> 6, c8 = (o >> 4) & 3;
            gload_lds16(W + (size_t)(n0 + row) * DD + t * 32 + c8 * 8,
                        lds + 24576 + t * 4096 + (wid << 10));
        }
    }

    for (int kt = 0; kt < 32; ++kt) {
        VWAIT(3);
        SB0();
        __builtin_amdgcn_s_barrier();
        SB0();
        {
            const int nk = (kt + 2 < 32) ? kt + 2 : 31;
            const int nb = (kt + 2) % 3;
            #pragma unroll
            for (int j2 = 0; j2 < 2; ++j2) {
                const int o = (j2 * 256 + tid) * 16;
                const int row = o >> 6, c8 = (o >> 4) & 3;
                gload_lds16(A + (size_t)(m0 + row) * DD + nk * 32 + c8 * 8,
                            lds + nb * 8192 + j2 * 4096 + (wid << 10));
            }
            {
                const int o = tid * 16;
                const int row = o >> 6, c8 = (o >> 4) & 3;
                gload_lds16(W + (size_t)(n0 + row) * DD + nk * 32 + c8 * 8,
                            lds + 24576 + nb * 4096 + (wid << 10));
            }
        }
        SB0();

        const int cb = kt % 3;
        const char* Ab = lds + cb * 8192;
        const char* Bb = lds + 24576 + cb * 4096;
        f16x8 af[2], bf[4];
        #pragma unroll
        for (int m = 0; m < 2; ++m)
            af[m] = *(const f16x8*)(Ab + (wm + m * 16 + lq) * 64 + lg * 16);
        #pragma unroll
        for (int n = 0; n < 4; ++n)
            bf[n] = *(const f16x8*)(Bb + (n * 16 + lq) * 64 + lg * 16);
        __builtin_amdgcn_s_setprio(1);
        #pragma unroll
        for (int m = 0; m < 2; ++m)
            #pragma unroll
            for (int n = 0; n < 4; ++n)
                acc[m][n] = __builtin_amdgcn_mfma_f32_16x16x32_f16(af[m], bf[n], acc[m][n], 0, 0, 0);
        __builtin_amdgcn_s_setprio(0);
    }

    #pragma unroll
    for (int m = 0; m < 2; ++m)
        #pragma unroll
        for (int n = 0; n < 4; ++n)
            #pragma unroll
            for (int r = 0; r < 4; ++r) {
                const int row = m0 + wm + m * 16 + lg * 4 + r;
                const int col = n0 + n * 16 + lq;
                C[(size_t)row * DD + col] = acc[m][n][r];
            }
}

// ---------------- Flash attention (unchanged from round 7) ----------------
template<bool TOPF16>
__global__ __launch_bounds__(256) void attn_fwd(const f16* __restrict__ Qp, const f16* __restrict__ Kp,
                                                const f16* __restrict__ VTp,
                                                const u64* __restrict__ Mp,
                                                f16* __restrict__ Op, void* __restrict__ topout,
                                                float* __restrict__ statsLinv) {
    extern __shared__ char lds[];
    const int tid = threadIdx.x, wid = tid >> 6, lane = tid & 63;
    const int lq = lane & 15, lg = lane >> 4;
    const int bid = blockIdx.x;
    const int xcd = bid & 7, j = bid >> 3;      // j 0..127
    const int bh = xcd * 4 + (j >> 5);          // 0..31
    const int qt = j & 31;
    const int b = bh >> 4, h = bh & 15;
    const bool topblk = (h == 0);
    const int qrow = qt * 64 + wid * 16 + lq;

    f16x8 qf[2];
    #pragma unroll
    for (int kk = 0; kk < 2; ++kk)
        qf[kk] = *(const f16x8*)(Qp + (size_t)(b * LL + qrow) * DD + h * 64 + (kk * 4 + lg) * 8);

    {
        #pragma unroll
        for (int jj = 0; jj < 2; ++jj) {
            const int o = (wid * 2 + jj) * 1024 + lane * 16;
            const int row = o >> 7, sc = ((o >> 4) & 7) ^ (row & 7);
            gload_lds16(Kp + (size_t)(b * LL + row) * DD + h * 64 + sc * 8,
                        lds + 8192 + (wid * 2 + jj) * 1024);
            gload_lds16(VTp + (size_t)((b * HH + h) * DHH + row) * LL + sc * 8,
                        lds + 24576 + (wid * 2 + jj) * 1024);
        }
    }

    float lsum = 0.f;
    f32x4 acc[4] = {};

    for (int kt = 0; kt < 32; ++kt) {
        if (topblk && kt > 0) { VWAIT(4); } else { VWAIT(0); }
        SB0();
        __builtin_amdgcn_s_barrier();
        SB0();
        const u64 cm = Mp[((size_t)b * 32 + kt) * LL + qrow];
        SB0();
        {
            const int nk = (kt + 1 < 32) ? kt + 1 : 31;
            const int nb = (kt + 1) & 1;
            #pragma unroll
            for (int jj = 0; jj < 2; ++jj) {
                const int o = (wid * 2 + jj) * 1024 + lane * 16;
                const int row = o >> 7, sc = ((o >> 4) & 7) ^ (row & 7);
                gload_lds16(Kp + (size_t)(b * LL + nk * 64 + row) * DD + h * 64 + sc * 8,
                            lds + 8192 + nb * 8192 + (wid * 2 + jj) * 1024);
                gload_lds16(VTp + (size_t)((b * HH + h) * DHH + row) * LL + nk * 64 + sc * 8,
                            lds + 24576 + nb * 8192 + (wid * 2 + jj) * 1024);
            }
        }
        SB0();

        const int cb = kt & 1;
        const char* Kb = lds + 8192 + cb * 8192;
        const char* Vb = lds + 24576 + cb * 8192;

        f32x4 s[4] = {};
        __builtin_amdgcn_s_setprio(1);
        #pragma unroll
        for (int f = 0; f < 4; ++f)
            #pragma unroll
            for (int kk = 0; kk < 2; ++kk) {
                const int co = (((kk * 4 + lg) ^ (lq & 7)) << 4);
                f16x8 kf = *(const f16x8*)(Kb + (f * 16 + lq) * 128 + co);
                s[f] = __builtin_amdgcn_mfma_f32_16x16x32_f16(kf, qf[kk], s[f], 0, 0, 0);
            }
        __builtin_amdgcn_s_setprio(0);

        const u64 wsh = cm >> (lg * 4);
        const unsigned lo = (unsigned)wsh, hi = (unsigned)(wsh >> 32);
        f16x4 ph[4];
        #pragma unroll
        for (int f = 0; f < 4; ++f) {
            const unsigned nib = ((f < 2) ? (lo >> (f * 16)) : (hi >> ((f - 2) * 16))) & 0xFu;
            #pragma unroll
            for (int r = 0; r < 4; ++r)
                if (nib & (1u << r)) s[f][r] = -1e18f;
            const float p0 = __builtin_amdgcn_exp2f(s[f][0]);
            const float p1 = __builtin_amdgcn_exp2f(s[f][1]);
            const float p2 = __builtin_amdgcn_exp2f(s[f][2]);
            const float p3 = __builtin_amdgcn_exp2f(s[f][3]);
            lsum += (p0 + p1) + (p2 + p3);
            f16x2 pa = __builtin_bit_cast(f16x2, __builtin_amdgcn_cvt_pkrtz(p0, p1));
            f16x2 pb = __builtin_bit_cast(f16x2, __builtin_amdgcn_cvt_pkrtz(p2, p3));
            ph[f][0] = pa[0]; ph[f][1] = pa[1]; ph[f][2] = pb[0]; ph[f][3] = pb[1];
        }

        if (topblk) {
            if (TOPF16) {
                f16* T = (f16*)topout;
                #pragma unroll
                for (int f = 0; f < 4; ++f)
                    *(f16x4*)(T + ((size_t)b * LL + qrow) * LL + kt * 64 + f * 16 + lg * 4) = ph[f];
            } else {
                float* T = (float*)topout;
                #pragma unroll
                for (int f = 0; f < 4; ++f)
                    *(f32x4*)(T + ((size_t)b * LL + qrow) * LL + kt * 64 + f * 16 + lg * 4) = s[f];
            }
        }

        #pragma unroll
        for (int f = 0; f < 4; ++f) {
            const int chunk = f * 2 + (lg >> 1);
            const int bo = ((chunk ^ (lq & 7)) << 4) + (lg & 1) * 8;
            *(f16x4*)(lds + (wid << 11) + lq * 128 + bo) = ph[f];
        }

        __builtin_amdgcn_s_setprio(1);
        #pragma unroll
        for (int kk = 0; kk < 2; ++kk) {
            const int co = (((kk * 4 + lg) ^ (lq & 7)) << 4);
            f16x8 pf = *(const f16x8*)(lds + (wid << 11) + lq * 128 + co);
            #pragma unroll
            for (int f = 0; f < 4; ++f) {
                f16x8 vf = *(const f16x8*)(Vb + (f * 16 + lq) * 128 + co);
                acc[f] = __builtin_amdgcn_mfma_f32_16x16x32_f16(vf, pf, acc[f], 0, 0, 0);
            }
        }
        __builtin_amdgcn_s_setprio(0);
    }

    lsum += __shfl_xor(lsum, 16);
    lsum += __shfl_xor(lsum, 32);
    const float linv = 1.f / lsum;
    #pragma unroll
    for (int f = 0; f < 4; ++f) {
        f16x4 ov;
        #pragma unroll
        for (int r = 0; r < 4; ++r) ov[r] = (f16)(acc[f][r] * linv);
        *(f16x4*)(Op + (size_t)(b * LL + qrow) * DD + h * 64 + f * 16 + lg * 4) = ov;
    }
    if (topblk && lg == 0) statsLinv[(size_t)b * LL + qrow] = linv;
}

// ---------------- top_attn finalize ----------------
template<bool TOPF16>
__global__ void norm_top(float* __restrict__ top, const void* __restrict__ src,
                         const float* __restrict__ linvp, int n) {
    int i = blockIdx.x * blockDim.x + threadIdx.x;
    const int stride = gridDim.x * blockDim.x;
    if (TOPF16) {
        const f16x8* s8 = (const f16x8*)src;
        for (; i < n; i += stride) {
            f16x8 v = s8[i];
            const float linv = linvp[(i * 8) >> 11];
            float4 a, bq;
            a.x = (float)v[0] * linv; a.y = (float)v[1] * linv;
            a.z = (float)v[2] * linv; a.w = (float)v[3] * linv;
            bq.x = (float)v[4] * linv; bq.y = (float)v[5] * linv;
            bq.z = (float)v[6] * linv; bq.w = (float)v[7] * linv;
            ((float4*)top)[i * 2] = a;
            ((float4*)top)[i * 2 + 1] = bq;
        }
    } else {
        for (; i < n; i += stride) {
            float4 v = ((const float4*)top)[i];
            const float linv = linvp[(i * 4) >> 11];
            v.x = __builtin_amdgcn_exp2f(v.x) * linv;
            v.y = __builtin_amdgcn_exp2f(v.y) * linv;
            v.z = __builtin_amdgcn_exp2f(v.z) * linv;
            v.w = __builtin_amdgcn_exp2f(v.w) * linv;
            ((float4*)top)[i] = v;
        }
    }
}

// ---------------- launch ----------------
extern "C" void kernel_launch(void* const* d_in, const int* in_sizes, int n_in,
                              void* d_out, int out_size, void* d_ws, size_t ws_size,
                              hipStream_t stream) {
    const float* q   = (const float*)d_in[0];
    const float* k   = (const float*)d_in[1];
    const float* v   = (const float*)d_in[2];
    const int*   msk = (const int*)d_in[3];
    const float* wq  = (const float*)d_in[4];
    const float* wk  = (const float*)d_in[5];
    const float* wv  = (const float*)d_in[6];
    const float* wo  = (const float*)d_in[7];
    float* out = (float*)d_out;

    const size_t NX = (size_t)BB * LL * DD;
    const size_t NW = (size_t)DD * DD;
    const int NMW = BB * LL * (LL / 64);
    const size_t NXo = NX;
    const float SCQ = 0.125f * 1.4426950408889634f;
    const int ALDS = 40960;

    f16* ws = (f16*)d_ws;
    const size_t needed = (6 * NX + 4 * NW) * 2 + (size_t)NMW * 8 + (size_t)BB * LL * 4;
    const bool fused = ws_size >= needed;

    if (fused) {
        f16* bufQ = ws;
        f16* bufK = bufQ + NX;
        f16* bufV = bufK + NX;
        f16* topP = bufK;               // overlays bufK+bufV (dead by attn time)
        f16* wh   = bufV + NX;
        f16* wqh = wh, *wkh = wh + NW, *wvh = wh + 2 * NW, *woh = wh + 3 * NW;
        f16* Qp  = wh + 4 * NW;
        f16* Kp  = Qp + NX;
        f16* VTp = Kp + NX;
        u64* Mp  = (u64*)(VTp + NX);
        float* statsLinv = (float*)(Mp + NMW);

        prep<<<dim3(1024, 5), 256, 0, stream>>>(q, k, v, msk, wq, wk, wv, wo,
                                                bufQ, bufK, bufV, wh, Mp, SCQ);
        gemm_qkv<<<768, 256, 0, stream>>>(bufQ, bufK, bufV, wqh, wkh, wvh, Qp, Kp, VTp);
        attn_fwd<true><<<1024, 256, ALDS, stream>>>(Qp, Kp, VTp, Mp, bufQ, topP, statsLinv);
        norm_top<true><<<2048, 256, 0, stream>>>(out + NXo, topP, statsLinv,
                                                 (int)((size_t)BB * LL * LL / 8));
        gemm_out<<<512, 256, 0, stream>>>(bufQ, woh, out);
    } else {
        f16* bufA = ws;
        f16* wh   = bufA + NX;
        f16* wqh = wh, *wkh = wh + NW, *wvh = wh + 2 * NW, *woh = wh + 3 * NW;
        f16* Qp  = wh + 4 * NW;
        f16* Kp  = Qp + NX;
        f16* VTp = Kp + NX;
        u64* Mp  = (u64*)(VTp + NX);
        float* statsLinv = (float*)(Mp + NMW);

        pack_mask<<<256, 256, 0, stream>>>(msk, Mp, NMW);
        cvt4_kernel<<<dim3(128, 4), 256, 0, stream>>>(wq, wk, wv, wo, wh, (int)(NW / 4));
        cvt_kernel<<<2048, 256, 0, stream>>>(q, bufA, (int)(NX / 4), SCQ);
        gemm_one<<<dim3(8, 32), 256, 0, stream>>>(bufA, wqh, Qp, 0);
        cvt_kernel<<<2048, 256, 0, stream>>>(k, bufA, (int)(NX / 4), 1.f);
        gemm_one<<<dim3(8, 32), 256, 0, stream>>>(bufA, wkh, Kp, 1);
        cvt_kernel<<<2048, 256, 0, stream>>>(v, bufA, (int)(NX / 4), 1.f);
        gemm_one<<<dim3(8, 32), 256, 0, stream>>>(bufA, wvh, VTp, 2);
        attn_fwd<false><<<1024, 256, ALDS, stream>>>(Qp, Kp, VTp, Mp, bufA,
                                                     out + NXo, statsLinv);
        norm_top<false><<<2048, 256, 0, stream>>>(out + NXo, out + NXo, statsLinv,
                                                  (int)((size_t)BB * LL * LL / 4));
        gemm_out<<<512, 256, 0, stream>>>(bufA, woh, out);
    }
}

// Round 9
// 155.309 us; speedup vs baseline: 1.4875x; 1.0755x over previous
//
#include <hip/hip_runtime.h>

#define BB 2
#define LL 2048
#define DD 1024
#define HH 16
#define DHH 64

typedef _Float16 f16;
typedef _Float16 f16x8 __attribute__((ext_vector_type(8)));
typedef _Float16 f16x4 __attribute__((ext_vector_type(4)));
typedef _Float16 f16x2 __attribute__((ext_vector_type(2)));
typedef float f32x4 __attribute__((ext_vector_type(4)));
typedef unsigned long long u64;

#define VWAIT(N) asm volatile("s_waitcnt vmcnt(" #N ")" ::: "memory")
#define LWAIT0() asm volatile("s_waitcnt lgkmcnt(0)" ::: "memory")
#define SB0() __builtin_amdgcn_sched_barrier(0)

__device__ __forceinline__ void gload_lds16(const void* g, void* l) {
    __builtin_amdgcn_global_load_lds(
        (const __attribute__((address_space(1))) void*)g,
        (__attribute__((address_space(3))) void*)l, 16, 0, 0);
}

__device__ __forceinline__ f16x4 cvt4f(float4 v) {
    f16x4 o;
    o[0] = (f16)v.x; o[1] = (f16)v.y; o[2] = (f16)v.z; o[3] = (f16)v.w;
    return o;
}

__device__ __forceinline__ f16x8 cvt8f(float4 a, float4 b) {
    f16x2 p0 = __builtin_bit_cast(f16x2, __builtin_amdgcn_cvt_pkrtz(a.x, a.y));
    f16x2 p1 = __builtin_bit_cast(f16x2, __builtin_amdgcn_cvt_pkrtz(a.z, a.w));
    f16x2 p2 = __builtin_bit_cast(f16x2, __builtin_amdgcn_cvt_pkrtz(b.x, b.y));
    f16x2 p3 = __builtin_bit_cast(f16x2, __builtin_amdgcn_cvt_pkrtz(b.z, b.w));
    f16x8 r;
    r[0] = p0[0]; r[1] = p0[1]; r[2] = p1[0]; r[3] = p1[1];
    r[4] = p2[0]; r[5] = p2[1]; r[6] = p3[0]; r[7] = p3[1];
    return r;
}

// ---------------- prep: mask pack + weight conversion (q/k/v conversion fused into GEMM) ----------------
__global__ void prep(const int* __restrict__ msk,
                     const float* __restrict__ wq, const float* __restrict__ wk,
                     const float* __restrict__ wv, const float* __restrict__ wo,
                     f16* __restrict__ wh, u64* __restrict__ Mp) {
    const int tid = threadIdx.x;
    if (blockIdx.y == 0) {
        const int lane = tid & 63;
        int w = (blockIdx.x * 256 + tid) >> 6;
        const int nw = (1024 * 256) >> 6;
        for (; w < BB * LL * 32; w += nw) {
            int mv = msk[(size_t)w * 64 + lane];
            u64 bits = __ballot(mv != 0);
            if (lane == 0) {
                const int kt = w & 31;
                const int bq = w >> 5;
                const int qq = bq & 2047, b = bq >> 11;
                Mp[((size_t)b * 32 + kt) * LL + qq] = bits;
            }
        }
    } else {
        int i = blockIdx.x * 256 + tid;
        const int stride = 1024 * 256;
        for (; i < 4 * 262144; i += stride) {
            const int sel = i >> 18, j = i & 262143;
            const float* s = sel == 0 ? wq : sel == 1 ? wk : sel == 2 ? wv : wo;
            ((f16x4*)wh)[i] = cvt4f(((const float4*)s)[j]);
        }
    }
}

// standalone pieces for the fallback path
__global__ void cvt_kernel(const float* __restrict__ src, f16* __restrict__ dst, int n4, float sc) {
    int i = blockIdx.x * blockDim.x + threadIdx.x;
    const int stride = gridDim.x * blockDim.x;
    for (; i < n4; i += stride) {
        float4 v = ((const float4*)src)[i];
        v.x *= sc; v.y *= sc; v.z *= sc; v.w *= sc;
        ((f16x4*)dst)[i] = cvt4f(v);
    }
}
__global__ void cvt4_kernel(const float* __restrict__ a, const float* __restrict__ b,
                            const float* __restrict__ c, const float* __restrict__ d,
                            f16* __restrict__ dst, int n4) {
    const float* s = blockIdx.y == 0 ? a : blockIdx.y == 1 ? b : blockIdx.y == 2 ? c : d;
    f16* o = dst + (size_t)blockIdx.y * n4 * 4;
    int i = blockIdx.x * blockDim.x + threadIdx.x;
    const int stride = gridDim.x * blockDim.x;
    for (; i < n4; i += stride)
        ((f16x4*)o)[i] = cvt4f(((const float4*)s)[i]);
}
__global__ void pack_mask(const int* __restrict__ mask, u64* __restrict__ out, int nwords) {
    const int lane = threadIdx.x & 63;
    int w = (blockIdx.x * blockDim.x + threadIdx.x) >> 6;
    const int nw = (gridDim.x * blockDim.x) >> 6;
    for (; w < nwords; w += nw) {
        int mv = mask[(size_t)w * 64 + lane];
        u64 bits = __ballot(mv != 0);
        if (lane == 0) {
            const int kt = w & 31;
            const int bq = w >> 5;
            const int qq = bq & 2047, b = bq >> 11;
            out[((size_t)b * 32 + kt) * LL + qq] = bits;
        }
    }
}

// ---------------- fused QKV projection GEMM with inline f32->f16 A conversion ----------------
// A is f32 (q/k/v inputs directly). A staged via reg (load dwordx4 x2 -> cvt_pkrtz -> ds_write_b128),
// W f16 via global_load_lds. 3-buffer LDS, depth-2, VWAIT(2) steady state. Full unroll so all
// reg-set / buffer indices are compile-time (rule #20). 768 blocks, XCD-swizzled.
// LDS 48KB: A 3x8K @0 | W 3x8K @24576.
__global__ __launch_bounds__(256) void gemm_qkv(
        const float* __restrict__ A0, const float* __restrict__ A1, const float* __restrict__ A2,
        const f16* __restrict__ W0, const f16* __restrict__ W1, const f16* __restrict__ W2,
        f16* __restrict__ C0, f16* __restrict__ C1, f16* __restrict__ C2, float scq) {
    __shared__ __align__(16) char lds[49152];
    const int bid = blockIdx.x;
    const int xcd = bid & 7, j = bid >> 3;      // j 0..95
    const int p = xcd * 12 + (j >> 3);          // A-panel index 0..95
    const int xb = j & 7;
    const int z = p >> 5, yb = p & 31;
    const float* __restrict__ A = z == 0 ? A0 : z == 1 ? A1 : A2;
    const f16* __restrict__ W = z == 0 ? W0 : z == 1 ? W1 : W2;
    f16* __restrict__ C       = z == 0 ? C0 : z == 1 ? C1 : C2;

    const int tid = threadIdx.x, wid = tid >> 6, lane = tid & 63;
    const int m0 = yb * 128, n0 = xb * 128;
    const int lq = lane & 15, lg = lane >> 4;
    const int wm = (wid >> 1) << 6, wn = (wid & 1) << 6;
    // A staging coords: slot jj covers rows (wid*2+jj)*16 + lane/4, 32B f32 chunk ac8
    const int ar0 = (wid * 2) * 16 + (lane >> 2);
    const int ar1 = (wid * 2 + 1) * 16 + (lane >> 2);
    const int ac8 = lane & 3;
    const float* a0p = A + (size_t)(m0 + ar0) * DD + ac8 * 8;
    const float* a1p = A + (size_t)(m0 + ar1) * DD + ac8 * 8;
    char* aw0 = lds + ar0 * 64 + ac8 * 16;      // + buf*8192
    char* aw1 = lds + ar1 * 64 + ac8 * 16;

    f32x4 acc[4][4] = {};
    float4 arA[2][2], arB[2][2];                // two reg sets, [slot][half]

    // ---- prologue: write A(0),A(1) to LDS; load A(2)->arA; issue W(0),W(1) ----
    {
        float4 t00 = *(const float4*)(a0p + 0 * 32);
        float4 t01 = *(const float4*)(a0p + 0 * 32 + 4);
        float4 t10 = *(const float4*)(a1p + 0 * 32);
        float4 t11 = *(const float4*)(a1p + 0 * 32 + 4);
        VWAIT(0);
        *(f16x8*)(aw0 + 0 * 8192) = cvt8f(t00, t01);
        *(f16x8*)(aw1 + 0 * 8192) = cvt8f(t10, t11);
        t00 = *(const float4*)(a0p + 1 * 32);
        t01 = *(const float4*)(a0p + 1 * 32 + 4);
        t10 = *(const float4*)(a1p + 1 * 32);
        t11 = *(const float4*)(a1p + 1 * 32 + 4);
        VWAIT(0);
        *(f16x8*)(aw0 + 1 * 8192) = cvt8f(t00, t01);
        *(f16x8*)(aw1 + 1 * 8192) = cvt8f(t10, t11);
        SB0();
        arA[0][0] = *(const float4*)(a0p + 2 * 32);
        arA[0][1] = *(const float4*)(a0p + 2 * 32 + 4);
        arA[1][0] = *(const float4*)(a1p + 2 * 32);
        arA[1][1] = *(const float4*)(a1p + 2 * 32 + 4);
        SB0();
        #pragma unroll
        for (int t = 0; t < 2; ++t)
            #pragma unroll
            for (int jj = 0; jj < 2; ++jj) {
                const int ldsoff = (wid * 2 + jj) << 10;
                const int o = ldsoff + lane * 16;
                const int row = o >> 6, c8 = (o >> 4) & 3;
                gload_lds16(W + (size_t)(n0 + row) * DD + t * 32 + c8 * 8,
                            lds + 24576 + t * 8192 + ldsoff);
            }
        LWAIT0();   // prologue ds_writes visible before first barrier
    }

    #pragma unroll
    for (int kt = 0; kt < 32; ++kt) {
        VWAIT(2);   // A(kt+2) regs + W(kt) done; W(kt+1) stays in flight
        SB0();
        __builtin_amdgcn_s_barrier();
        SB0();
        // ds_write A(kt+2) from reg set (kt&1); load A(kt+3) into the other set
        {
            const int wb = (kt + 2) % 3;
            const int nk = (kt + 3 < 32) ? kt + 3 : 31;
            if ((kt & 1) == 0) {
                *(f16x8*)(aw0 + wb * 8192) = cvt8f(arA[0][0], arA[0][1]);
                *(f16x8*)(aw1 + wb * 8192) = cvt8f(arA[1][0], arA[1][1]);
                SB0();
                arB[0][0] = *(const float4*)(a0p + nk * 32);
                arB[0][1] = *(const float4*)(a0p + nk * 32 + 4);
                arB[1][0] = *(const float4*)(a1p + nk * 32);
                arB[1][1] = *(const float4*)(a1p + nk * 32 + 4);
            } else {
                *(f16x8*)(aw0 + wb * 8192) = cvt8f(arB[0][0], arB[0][1]);
                *(f16x8*)(aw1 + wb * 8192) = cvt8f(arB[1][0], arB[1][1]);
                SB0();
                arA[0][0] = *(const float4*)(a0p + nk * 32);
                arA[0][1] = *(const float4*)(a0p + nk * 32 + 4);
                arA[1][0] = *(const float4*)(a1p + nk * 32);
                arA[1][1] = *(const float4*)(a1p + nk * 32 + 4);
            }
        }
        SB0();
        // issue W(kt+2) staged loads (after A loads: keeps vmcnt ordering A then W)
        {
            const int nk = (kt + 2 < 32) ? kt + 2 : 31;
            const int nb = (kt + 2) % 3;
            #pragma unroll
            for (int jj = 0; jj < 2; ++jj) {
                const int ldsoff = (wid * 2 + jj) << 10;
                const int o = ldsoff + lane * 16;
                const int row = o >> 6, c8 = (o >> 4) & 3;
                gload_lds16(W + (size_t)(n0 + row) * DD + nk * 32 + c8 * 8,
                            lds + 24576 + nb * 8192 + ldsoff);
            }
        }
        SB0();

        const int cb = kt % 3;
        const char* Ab = lds + cb * 8192;
        const char* Bb = lds + 24576 + cb * 8192;
        f16x8 af[4], bf[4];
        #pragma unroll
        for (int m = 0; m < 4; ++m)
            af[m] = *(const f16x8*)(Ab + (wm + m * 16 + lq) * 64 + lg * 16);
        #pragma unroll
        for (int n = 0; n < 4; ++n)
            bf[n] = *(const f16x8*)(Bb + (wn + n * 16 + lq) * 64 + lg * 16);
        __builtin_amdgcn_s_setprio(1);
        #pragma unroll
        for (int m = 0; m < 4; ++m)
            #pragma unroll
            for (int n = 0; n < 4; ++n)
                acc[m][n] = __builtin_amdgcn_mfma_f32_16x16x32_f16(af[m], bf[n], acc[m][n], 0, 0, 0);
        __builtin_amdgcn_s_setprio(0);
    }

    const float oscale = (z == 0) ? scq : 1.0f;
    #pragma unroll
    for (int m = 0; m < 4; ++m)
        #pragma unroll
        for (int n = 0; n < 4; ++n)
            #pragma unroll
            for (int r = 0; r < 4; ++r) {
                const int row = m0 + wm + m * 16 + lg * 4 + r;
                const int col = n0 + wn + n * 16 + lq;
                const float val = acc[m][n][r] * oscale;
                if (z < 2) {
                    C[(size_t)row * DD + col] = (f16)val;
                } else {
                    const int b = row >> 11, l = row & 2047;
                    const int h = col >> 6, dh = col & 63;
                    C[((size_t)((b * HH + h) * DHH + dh) << 11) + l] = (f16)val;
                }
            }
}

// ---------------- fallback f16-input GEMM (round-8 structure) ----------------
__global__ __launch_bounds__(256) void gemm_one(const f16* __restrict__ A, const f16* __restrict__ W,
                                                f16* __restrict__ C, int z) {
    __shared__ __align__(16) char lds[49152];
    const int tid = threadIdx.x, wid = tid >> 6, lane = tid & 63;
    const int m0 = blockIdx.y * 128, n0 = blockIdx.x * 128;
    const int lq = lane & 15, lg = lane >> 4;
    const int wm = (wid >> 1) << 6, wn = (wid & 1) << 6;
    f32x4 acc[4][4] = {};

    #pragma unroll
    for (int t = 0; t < 2; ++t)
        #pragma unroll
        for (int jj = 0; jj < 2; ++jj) {
            const int ldsoff = (wid * 2 + jj) << 10;
            const int o = ldsoff + lane * 16;
            const int row = o >> 6, c8 = (o >> 4) & 3;
            gload_lds16(A + (size_t)(m0 + row) * DD + t * 32 + c8 * 8, lds + t * 8192 + ldsoff);
            gload_lds16(W + (size_t)(n0 + row) * DD + t * 32 + c8 * 8, lds + 24576 + t * 8192 + ldsoff);
        }

    for (int kt = 0; kt < 32; ++kt) {
        VWAIT(4);
        SB0();
        __builtin_amdgcn_s_barrier();
        SB0();
        {
            const int nk = (kt + 2 < 32) ? kt + 2 : 31;
            const int nb = (kt + 2) % 3;
            #pragma unroll
            for (int jj = 0; jj < 2; ++jj) {
                const int ldsoff = (wid * 2 + jj) << 10;
                const int o = ldsoff + lane * 16;
                const int row = o >> 6, c8 = (o >> 4) & 3;
                gload_lds16(A + (size_t)(m0 + row) * DD + nk * 32 + c8 * 8,
                            lds + nb * 8192 + ldsoff);
                gload_lds16(W + (size_t)(n0 + row) * DD + nk * 32 + c8 * 8,
                            lds + 24576 + nb * 8192 + ldsoff);
            }
        }
        SB0();

        const int cb = kt % 3;
        const char* Ab = lds + cb * 8192;
        const char* Bb = lds + 24576 + cb * 8192;
        f16x8 af[4], bf[4];
        #pragma unroll
        for (int m = 0; m < 4; ++m)
            af[m] = *(const f16x8*)(Ab + (wm + m * 16 + lq) * 64 + lg * 16);
        #pragma unroll
        for (int n = 0; n < 4; ++n)
            bf[n] = *(const f16x8*)(Bb + (wn + n * 16 + lq) * 64 + lg * 16);
        __builtin_amdgcn_s_setprio(1);
        #pragma unroll
        for (int m = 0; m < 4; ++m)
            #pragma unroll
            for (int n = 0; n < 4; ++n)
                acc[m][n] = __builtin_amdgcn_mfma_f32_16x16x32_f16(af[m], bf[n], acc[m][n], 0, 0, 0);
        __builtin_amdgcn_s_setprio(0);
    }

    #pragma unroll
    for (int m = 0; m < 4; ++m)
        #pragma unroll
        for (int n = 0; n < 4; ++n)
            #pragma unroll
            for (int r = 0; r < 4; ++r) {
                const int row = m0 + wm + m * 16 + lg * 4 + r;
                const int col = n0 + wn + n * 16 + lq;
                const float val = acc[m][n][r];
                if (z < 2) {
                    C[(size_t)row * DD + col] = (f16)val;
                } else {
                    const int b = row >> 11, l = row & 2047;
                    const int h = col >> 6, dh = col & 63;
                    C[((size_t)((b * HH + h) * DHH + dh) << 11) + l] = (f16)val;
                }
            }
}

// ---------------- finale: gemm_out (blocks 0..511) + top_attn normalize (blocks 512..1535) ----------------
template<bool TOPF16>
__global__ __launch_bounds__(256) void finale(const f16* __restrict__ A, const f16* __restrict__ W,
                                              float* __restrict__ C, float* __restrict__ top,
                                              const void* __restrict__ src,
                                              const float* __restrict__ linvp) {
    __shared__ __align__(16) char lds[36864];
    const int tid = threadIdx.x;
    if (blockIdx.x >= 512) {
        // ---- normalize branch ----
        int i = (blockIdx.x - 512) * 256 + tid;
        const int stride = 1024 * 256;
        if (TOPF16) {
            const f16x8* s8 = (const f16x8*)src;
            const int n = (int)((size_t)BB * LL * LL / 8);
            for (; i < n; i += stride) {
                f16x8 v = s8[i];
                const float linv = linvp[(i * 8) >> 11];
                float4 a, bq;
                a.x = (float)v[0] * linv; a.y = (float)v[1] * linv;
                a.z = (float)v[2] * linv; a.w = (float)v[3] * linv;
                bq.x = (float)v[4] * linv; bq.y = (float)v[5] * linv;
                bq.z = (float)v[6] * linv; bq.w = (float)v[7] * linv;
                ((float4*)top)[i * 2] = a;
                ((float4*)top)[i * 2 + 1] = bq;
            }
        } else {
            const int n = (int)((size_t)BB * LL * LL / 4);
            for (; i < n; i += stride) {
                float4 v = ((const float4*)top)[i];
                const float linv = linvp[(i * 4) >> 11];
                v.x = __builtin_amdgcn_exp2f(v.x) * linv;
                v.y = __builtin_amdgcn_exp2f(v.y) * linv;
                v.z = __builtin_amdgcn_exp2f(v.z) * linv;
                v.w = __builtin_amdgcn_exp2f(v.w) * linv;
                ((float4*)top)[i] = v;
            }
        }
        return;
    }
    // ---- output projection branch: 128x64 tile, XCD-swizzled ----
    const int bid = blockIdx.x;
    const int xcd = bid & 7, j = bid >> 3;
    const int yb = xcd * 4 + (j >> 4);
    const int xb = j & 15;
    const int wid = tid >> 6, lane = tid & 63;
    const int m0 = yb * 128, n0 = xb * 64;
    const int lq = lane & 15, lg = lane >> 4;
    const int wm = wid * 32;
    f32x4 acc[2][4] = {};

    #pragma unroll
    for (int t = 0; t < 2; ++t) {
        #pragma unroll
        for (int j2 = 0; j2 < 2; ++j2) {
            const int o = (j2 * 256 + tid) * 16;
            const int row = o >> 6, c8 = (o >> 4) & 3;
            gload_lds16(A + (size_t)(m0 + row) * DD + t * 32 + c8 * 8,
                        lds + t * 8192 + j2 * 4096 + (wid << 10));
        }
        {
            const int o = tid * 16;
            const int row = o >> 6, c8 = (o >> 4) & 3;
            gload_lds16(W + (size_t)(n0 + row) * DD + t * 32 + c8 * 8,
                        lds + 24576 + t * 4096 + (wid << 10));
        }
    }

    for (int kt = 0; kt < 32; ++kt) {
        VWAIT(3);
        SB0();
        __builtin_amdgcn_s_barrier();
        SB0();
        {
            const int nk = (kt + 2 < 32) ? kt + 2 : 31;
            const int nb = (kt + 2) % 3;
            #pragma unroll
            for (int j2 = 0; j2 < 2; ++j2) {
                const int o = (j2 * 256 + tid) * 16;
                const int row = o >> 6, c8 = (o >> 4) & 3;
                gload_lds16(A + (size_t)(m0 + row) * DD + nk * 32 + c8 * 8,
                            lds + nb * 8192 + j2 * 4096 + (wid << 10));
            }
            {
                const int o = tid * 16;
                const int row = o >> 6, c8 = (o >> 4) & 3;
                gload_lds16(W + (size_t)(n0 + row) * DD + nk * 32 + c8 * 8,
                            lds + 24576 + nb * 4096 + (wid << 10));
            }
        }
        SB0();

        const int cb = kt % 3;
        const char* Ab = lds + cb * 8192;
        const char* Bb = lds + 24576 + cb * 4096;
        f16x8 af[2], bf[4];
        #pragma unroll
        for (int m = 0; m < 2; ++m)
            af[m] = *(const f16x8*)(Ab + (wm + m * 16 + lq) * 64 + lg * 16);
        #pragma unroll
        for (int n = 0; n < 4; ++n)
            bf[n] = *(const f16x8*)(Bb + (n * 16 + lq) * 64 + lg * 16);
        __builtin_amdgcn_s_setprio(1);
        #pragma unroll
        for (int m = 0; m < 2; ++m)
            #pragma unroll
            for (int n = 0; n < 4; ++n)
                acc[m][n] = __builtin_amdgcn_mfma_f32_16x16x32_f16(af[m], bf[n], acc[m][n], 0, 0, 0);
        __builtin_amdgcn_s_setprio(0);
    }

    #pragma unroll
    for (int m = 0; m < 2; ++m)
        #pragma unroll
        for (int n = 0; n < 4; ++n)
            #pragma unroll
            for (int r = 0; r < 4; ++r) {
                const int row = m0 + wm + m * 16 + lg * 4 + r;
                const int col = n0 + n * 16 + lq;
                C[(size_t)row * DD + col] = acc[m][n][r];
            }
}

// ---------------- Flash attention (unchanged from round 7/8) ----------------
template<bool TOPF16>
__global__ __launch_bounds__(256) void attn_fwd(const f16* __restrict__ Qp, const f16* __restrict__ Kp,
                                                const f16* __restrict__ VTp,
                                                const u64* __restrict__ Mp,
                                                f16* __restrict__ Op, void* __restrict__ topout,
                                                float* __restrict__ statsLinv) {
    extern __shared__ char lds[];
    const int tid = threadIdx.x, wid = tid >> 6, lane = tid & 63;
    const int lq = lane & 15, lg = lane >> 4;
    const int bid = blockIdx.x;
    const int xcd = bid & 7, j = bid >> 3;
    const int bh = xcd * 4 + (j >> 5);
    const int qt = j & 31;
    const int b = bh >> 4, h = bh & 15;
    const bool topblk = (h == 0);
    const int qrow = qt * 64 + wid * 16 + lq;

    f16x8 qf[2];
    #pragma unroll
    for (int kk = 0; kk < 2; ++kk)
        qf[kk] = *(const f16x8*)(Qp + (size_t)(b * LL + qrow) * DD + h * 64 + (kk * 4 + lg) * 8);

    {
        #pragma unroll
        for (int jj = 0; jj < 2; ++jj) {
            const int o = (wid * 2 + jj) * 1024 + lane * 16;
            const int row = o >> 7, sc = ((o >> 4) & 7) ^ (row & 7);
            gload_lds16(Kp + (size_t)(b * LL + row) * DD + h * 64 + sc * 8,
                        lds + 8192 + (wid * 2 + jj) * 1024);
            gload_lds16(VTp + (size_t)((b * HH + h) * DHH + row) * LL + sc * 8,
                        lds + 24576 + (wid * 2 + jj) * 1024);
        }
    }

    float lsum = 0.f;
    f32x4 acc[4] = {};

    for (int kt = 0; kt < 32; ++kt) {
        if (topblk && kt > 0) { VWAIT(4); } else { VWAIT(0); }
        SB0();
        __builtin_amdgcn_s_barrier();
        SB0();
        const u64 cm = Mp[((size_t)b * 32 + kt) * LL + qrow];
        SB0();
        {
            const int nk = (kt + 1 < 32) ? kt + 1 : 31;
            const int nb = (kt + 1) & 1;
            #pragma unroll
            for (int jj = 0; jj < 2; ++jj) {
                const int o = (wid * 2 + jj) * 1024 + lane * 16;
                const int row = o >> 7, sc = ((o >> 4) & 7) ^ (row & 7);
                gload_lds16(Kp + (size_t)(b * LL + nk * 64 + row) * DD + h * 64 + sc * 8,
                            lds + 8192 + nb * 8192 + (wid * 2 + jj) * 1024);
                gload_lds16(VTp + (size_t)((b * HH + h) * DHH + row) * LL + nk * 64 + sc * 8,
                            lds + 24576 + nb * 8192 + (wid * 2 + jj) * 1024);
            }
        }
        SB0();

        const int cb = kt & 1;
        const char* Kb = lds + 8192 + cb * 8192;
        const char* Vb = lds + 24576 + cb * 8192;

        f32x4 s[4] = {};
        __builtin_amdgcn_s_setprio(1);
        #pragma unroll
        for (int f = 0; f < 4; ++f)
            #pragma unroll
            for (int kk = 0; kk < 2; ++kk) {
                const int co = (((kk * 4 + lg) ^ (lq & 7)) << 4);
                f16x8 kf = *(const f16x8*)(Kb + (f * 16 + lq) * 128 + co);
                s[f] = __builtin_amdgcn_mfma_f32_16x16x32_f16(kf, qf[kk], s[f], 0, 0, 0);
            }
        __builtin_amdgcn_s_setprio(0);

        const u64 wsh = cm >> (lg * 4);
        const unsigned lo = (unsigned)wsh, hi = (unsigned)(wsh >> 32);
        f16x4 ph[4];
        #pragma unroll
        for (int f = 0; f < 4; ++f) {
            const unsigned nib = ((f < 2) ? (lo >> (f * 16)) : (hi >> ((f - 2) * 16))) & 0xFu;
            #pragma unroll
            for (int r = 0; r < 4; ++r)
                if (nib & (1u << r)) s[f][r] = -1e18f;
            const float p0 = __builtin_amdgcn_exp2f(s[f][0]);
            const float p1 = __builtin_amdgcn_exp2f(s[f][1]);
            const float p2 = __builtin_amdgcn_exp2f(s[f][2]);
            const float p3 = __builtin_amdgcn_exp2f(s[f][3]);
            lsum += (p0 + p1) + (p2 + p3);
            f16x2 pa = __builtin_bit_cast(f16x2, __builtin_amdgcn_cvt_pkrtz(p0, p1));
            f16x2 pb = __builtin_bit_cast(f16x2, __builtin_amdgcn_cvt_pkrtz(p2, p3));
            ph[f][0] = pa[0]; ph[f][1] = pa[1]; ph[f][2] = pb[0]; ph[f][3] = pb[1];
        }

        if (topblk) {
            if (TOPF16) {
                f16* T = (f16*)topout;
                #pragma unroll
                for (int f = 0; f < 4; ++f)
                    *(f16x4*)(T + ((size_t)b * LL + qrow) * LL + kt * 64 + f * 16 + lg * 4) = ph[f];
            } else {
                float* T = (float*)topout;
                #pragma unroll
                for (int f = 0; f < 4; ++f)
                    *(f32x4*)(T + ((size_t)b * LL + qrow) * LL + kt * 64 + f * 16 + lg * 4) = s[f];
            }
        }

        #pragma unroll
        for (int f = 0; f < 4; ++f) {
            const int chunk = f * 2 + (lg >> 1);
            const int bo = ((chunk ^ (lq & 7)) << 4) + (lg & 1) * 8;
            *(f16x4*)(lds + (wid << 11) + lq * 128 + bo) = ph[f];
        }

        __builtin_amdgcn_s_setprio(1);
        #pragma unroll
        for (int kk = 0; kk < 2; ++kk) {
            const int co = (((kk * 4 + lg) ^ (lq & 7)) << 4);
            f16x8 pf = *(const f16x8*)(lds + (wid << 11) + lq * 128 + co);
            #pragma unroll
            for (int f = 0; f < 4; ++f) {
                f16x8 vf = *(const f16x8*)(Vb + (f * 16 + lq) * 128 + co);
                acc[f] = __builtin_amdgcn_mfma_f32_16x16x32_f16(vf, pf, acc[f], 0, 0, 0);
            }
        }
        __builtin_amdgcn_s_setprio(0);
    }

    lsum += __shfl_xor(lsum, 16);
    lsum += __shfl_xor(lsum, 32);
    const float linv = 1.f / lsum;
    #pragma unroll
    for (int f = 0; f < 4; ++f) {
        f16x4 ov;
        #pragma unroll
        for (int r = 0; r < 4; ++r) ov[r] = (f16)(acc[f][r] * linv);
        *(f16x4*)(Op + (size_t)(b * LL + qrow) * DD + h * 64 + f * 16 + lg * 4) = ov;
    }
    if (topblk && lg == 0) statsLinv[(size_t)b * LL + qrow] = linv;
}

// ---------------- launch ----------------
extern "C" void kernel_launch(void* const* d_in, const int* in_sizes, int n_in,
                              void* d_out, int out_size, void* d_ws, size_t ws_size,
                              hipStream_t stream) {
    const float* q   = (const float*)d_in[0];
    const float* k   = (const float*)d_in[1];
    const float* v   = (const float*)d_in[2];
    const int*   msk = (const int*)d_in[3];
    const float* wq  = (const float*)d_in[4];
    const float* wk  = (const float*)d_in[5];
    const float* wv  = (const float*)d_in[6];
    const float* wo  = (const float*)d_in[7];
    float* out = (float*)d_out;

    const size_t NX = (size_t)BB * LL * DD;
    const size_t NW = (size_t)DD * DD;
    const int NMW = BB * LL * (LL / 64);
    const size_t NXo = NX;
    const float SCQ = 0.125f * 1.4426950408889634f;
    const int ALDS = 40960;

    f16* ws = (f16*)d_ws;
    const size_t needed = (6 * NX + 4 * NW) * 2 + (size_t)NMW * 8 + (size_t)BB * LL * 4;
    const bool fused = ws_size >= needed;

    if (fused) {
        // layout: Op NX | wh 4NW | Qp NX | Kp NX | VTp NX | topP 2NX | Mp | stats
        f16* Op   = ws;
        f16* wh   = Op + NX;
        f16* wqh = wh, *wkh = wh + NW, *wvh = wh + 2 * NW, *woh = wh + 3 * NW;
        f16* Qp  = wh + 4 * NW;
        f16* Kp  = Qp + NX;
        f16* VTp = Kp + NX;
        f16* topP = VTp + NX;
        u64* Mp  = (u64*)(topP + 2 * NX);
        float* statsLinv = (float*)(Mp + NMW);

        prep<<<dim3(1024, 2), 256, 0, stream>>>(msk, wq, wk, wv, wo, wh, Mp);
        gemm_qkv<<<768, 256, 0, stream>>>(q, k, v, wqh, wkh, wvh, Qp, Kp, VTp, SCQ);
        attn_fwd<true><<<1024, 256, ALDS, stream>>>(Qp, Kp, VTp, Mp, Op, topP, statsLinv);
        finale<true><<<1536, 256, 0, stream>>>(Op, woh, out, out + NXo, topP, statsLinv);
    } else {
        f16* bufA = ws;
        f16* wh   = bufA + NX;
        f16* wqh = wh, *wkh = wh + NW, *wvh = wh + 2 * NW, *woh = wh + 3 * NW;
        f16* Qp  = wh + 4 * NW;
        f16* Kp  = Qp + NX;
        f16* VTp = Kp + NX;
        u64* Mp  = (u64*)(VTp + NX);
        float* statsLinv = (float*)(Mp + NMW);

        pack_mask<<<256, 256, 0, stream>>>(msk, Mp, NMW);
        cvt4_kernel<<<dim3(128, 4), 256, 0, stream>>>(wq, wk, wv, wo, wh, (int)(NW / 4));
        cvt_kernel<<<2048, 256, 0, stream>>>(q, bufA, (int)(NX / 4), SCQ);
        gemm_one<<<dim3(8, 32), 256, 0, stream>>>(bufA, wqh, Qp, 0);
        cvt_kernel<<<2048, 256, 0, stream>>>(k, bufA, (int)(NX / 4), 1.f);
        gemm_one<<<dim3(8, 32), 256, 0, stream>>>(bufA, wkh, Kp, 1);
        cvt_kernel<<<2048, 256, 0, stream>>>(v, bufA, (int)(NX / 4), 1.f);
        gemm_one<<<dim3(8, 32), 256, 0, stream>>>(bufA, wvh, VTp, 2);
        attn_fwd<false><<<1024, 256, ALDS, stream>>>(Qp, Kp, VTp, Mp, bufA,
                                                     out + NXo, statsLinv);
        finale<false><<<1536, 256, 0, stream>>>(bufA, woh, out, out + NXo, out + NXo, statsLinv);
    }
}